// Round 1
// baseline (250.433 us; speedup 1.0000x reference)
//
#include <hip/hip_runtime.h>
#include <math.h>

#define HH 16
#define DM 1024
#define DK 64
#define NE 40001
#define NB 2
#define NQS 512
#define NKS 512

// ---------------------------------------------------------------------------
// Kernel 1: project embedding tables through Wb:
//   xproj[i][h] = sum_d x_table[i, h*16+d] * Wb[d]   (Wb shared across heads)
// ---------------------------------------------------------------------------
__global__ __launch_bounds__(256) void proj_tables_k(
    const float* __restrict__ xt, const float* __restrict__ yt,
    const float* __restrict__ Wb,
    float* __restrict__ xproj, float* __restrict__ yproj)
{
    int gid = blockIdx.x * 256 + threadIdx.x;
    const int tot = NE * HH;            // 640016
    if (gid >= 2 * tot) return;
    const float* tab = xt;
    float* dst = xproj;
    int r = gid;
    if (r >= tot) { r -= tot; tab = yt; dst = yproj; }
    int i = r >> 4, h = r & 15;
    const float* p = tab + i * 256 + h * 16;
    float s = 0.f;
#pragma unroll
    for (int d = 0; d < 16; ++d) s += p[d] * Wb[d];
    dst[r] = s;
}

// ---------------------------------------------------------------------------
// Kernel 2: GEMM  Y = X(1024x1024) @ W(1024x1024) + bias
// qkv==1: grid.z in {0,1,2} selects (Q,K,V); epilogue scatters:
//   z=0,2 -> (B,H,N,64) layout ; z=1 -> (B,H,64,N) transposed layout
// qkv==0: plain row-major 1024x1024 output (the Wo projection)
// ---------------------------------------------------------------------------
__global__ __launch_bounds__(256) void gemm_k(
    const float* __restrict__ X0, const float* __restrict__ X1, const float* __restrict__ X2,
    const float* __restrict__ W0, const float* __restrict__ W1, const float* __restrict__ W2,
    const float* __restrict__ B0, const float* __restrict__ B1, const float* __restrict__ B2,
    float* __restrict__ Y0, float* __restrict__ Y1, float* __restrict__ Y2,
    int qkv)
{
    __shared__ float Xs[32][68];   // [k][m] transposed
    __shared__ float Wsh[32][68];  // [k][n]
    const int z = blockIdx.z;
    const float* X = (z == 0) ? X0 : ((z == 1) ? X1 : X2);
    const float* W = (z == 0) ? W0 : ((z == 1) ? W1 : W2);
    const float* Bv = (z == 0) ? B0 : ((z == 1) ? B1 : B2);
    float* Y = (z == 0) ? Y0 : ((z == 1) ? Y1 : Y2);
    const int m0 = blockIdx.y * 64, n0 = blockIdx.x * 64;
    const int tid = threadIdx.x;
    const int tr = (tid >> 4) << 2, tc = (tid & 15) << 2;
    float acc[4][4] = {};

    for (int k0 = 0; k0 < 1024; k0 += 32) {
#pragma unroll
        for (int half = 0; half < 2; ++half) {
            int f = (tid + half * 256) * 4;
            int m = f >> 5, kc = f & 31;
            float4 v = *(const float4*)(X + (m0 + m) * 1024 + k0 + kc);
            Xs[kc + 0][m] = v.x; Xs[kc + 1][m] = v.y; Xs[kc + 2][m] = v.z; Xs[kc + 3][m] = v.w;
            int rr = f >> 6, cc = f & 63;
            *(float4*)&Wsh[rr][cc] = *(const float4*)(W + (k0 + rr) * 1024 + n0 + cc);
        }
        __syncthreads();
#pragma unroll
        for (int kk = 0; kk < 32; ++kk) {
            float4 a = *(const float4*)&Xs[kk][tr];
            float4 bv4 = *(const float4*)&Wsh[kk][tc];
            acc[0][0] += a.x * bv4.x; acc[0][1] += a.x * bv4.y; acc[0][2] += a.x * bv4.z; acc[0][3] += a.x * bv4.w;
            acc[1][0] += a.y * bv4.x; acc[1][1] += a.y * bv4.y; acc[1][2] += a.y * bv4.z; acc[1][3] += a.y * bv4.w;
            acc[2][0] += a.z * bv4.x; acc[2][1] += a.z * bv4.y; acc[2][2] += a.z * bv4.z; acc[2][3] += a.z * bv4.w;
            acc[3][0] += a.w * bv4.x; acc[3][1] += a.w * bv4.y; acc[3][2] += a.w * bv4.z; acc[3][3] += a.w * bv4.w;
        }
        __syncthreads();
    }

    if (!qkv) {
        float4 bv4 = *(const float4*)(Bv + n0 + tc);
#pragma unroll
        for (int i = 0; i < 4; ++i) {
            int row = m0 + tr + i;
            float4 o;
            o.x = acc[i][0] + bv4.x; o.y = acc[i][1] + bv4.y;
            o.z = acc[i][2] + bv4.z; o.w = acc[i][3] + bv4.w;
            *(float4*)(Y + row * 1024 + n0 + tc) = o;
        }
    } else if (z != 1) {
        // (B,H,N,64)
        float4 bv4 = *(const float4*)(Bv + n0 + tc);
        int col = n0 + tc, hh = col >> 6, dd = col & 63;
#pragma unroll
        for (int i = 0; i < 4; ++i) {
            int row = m0 + tr + i, bb_ = row >> 9, nn = row & 511;
            float4 o;
            o.x = acc[i][0] + bv4.x; o.y = acc[i][1] + bv4.y;
            o.z = acc[i][2] + bv4.z; o.w = acc[i][3] + bv4.w;
            *(float4*)(Y + ((bb_ * HH + hh) * NQS + nn) * DK + dd) = o;
        }
    } else {
        // K transposed: (B,H,64,N)
        int row0 = m0 + tr, bb_ = row0 >> 9, nn = row0 & 511;
#pragma unroll
        for (int j = 0; j < 4; ++j) {
            int col = n0 + tc + j, hh = col >> 6, dd = col & 63;
            float bj = Bv[col];
            float4 o;
            o.x = acc[0][j] + bj; o.y = acc[1][j] + bj;
            o.z = acc[2][j] + bj; o.w = acc[3][j] + bj;
            *(float4*)(Y + ((bb_ * HH + hh) * DK + dd) * NKS + nn) = o;
        }
    }
}

// ---------------------------------------------------------------------------
// Kernel 3: fused attention with position bias, online softmax (flash-style).
// Block = (q-tile of 32, h, b). 256 threads: qg=tid>>4 (2 q rows each),
// tg=tid&15 (4 k cols in score phase / 4 d cols in PV phase).
// ---------------------------------------------------------------------------
__global__ __launch_bounds__(256) void attn_k(
    const float* __restrict__ qbuf, const float* __restrict__ kbufT, const float* __restrict__ vbuf,
    const float* __restrict__ xproj, const float* __restrict__ yproj,
    const float* __restrict__ qx, const float* __restrict__ qy,
    const float* __restrict__ kx, const float* __restrict__ ky,
    const float* __restrict__ bbp,
    float* __restrict__ attb)
{
    __shared__ float qsT[64][36];   // [d][q]
    __shared__ float kT[64][68];    // [d][k-chunk]
    __shared__ float vsh[64][68];   // [k-chunk][d]
    __shared__ float pT[64][36];    // [k-chunk][q]
    __shared__ float qxk[64], qyk[64], kxq[32], kyq[32];

    const int tid = threadIdx.x;
    const int q0 = blockIdx.x * 32;
    const int h = blockIdx.y;
    const int b = blockIdx.z;
    const int bh = b * HH + h;

    // stage Q tile transposed + q-side key positions
#pragma unroll
    for (int t = 0; t < 2; ++t) {
        int f = (tid + t * 256) * 4;
        int q = f >> 6, c = f & 63;
        float4 v = *(const float4*)(qbuf + (bh * NQS + q0 + q) * DK + c);
        qsT[c + 0][q] = v.x; qsT[c + 1][q] = v.y; qsT[c + 2][q] = v.z; qsT[c + 3][q] = v.w;
    }
    if (tid < 32) { kxq[tid] = kx[b * NQS + q0 + tid]; kyq[tid] = ky[b * NQS + q0 + tid]; }
    const float bbv = bbp[0];

    const int qg = tid >> 4, tg = tid & 15;
    float acc[2][4] = {{0.f,0.f,0.f,0.f},{0.f,0.f,0.f,0.f}};
    float mrun[2] = {-1e30f, -1e30f};
    float lsum[2] = {0.f, 0.f};

    for (int kc = 0; kc < NKS; kc += 64) {
        __syncthreads();   // protect LDS reuse across iterations (and Q staging for iter 0)
        if (tid < 64) { qxk[tid] = qx[b * NKS + kc + tid]; qyk[tid] = qy[b * NKS + kc + tid]; }
#pragma unroll
        for (int t = 0; t < 4; ++t) {
            int f = (tid + t * 256) * 4;
            int d = f >> 6, c = f & 63;
            *(float4*)&kT[d][c]  = *(const float4*)(kbufT + (bh * DK + d) * NKS + kc + c);
            *(float4*)&vsh[d][c] = *(const float4*)(vbuf + (bh * NKS + kc + d) * DK + c);
        }
        __syncthreads();

        // scores: s[q 2][k 4] over d=0..63
        float s[2][4] = {{0.f,0.f,0.f,0.f},{0.f,0.f,0.f,0.f}};
#pragma unroll 16
        for (int d = 0; d < 64; ++d) {
            float2 a = *(const float2*)&qsT[d][qg * 2];
            float4 kv = *(const float4*)&kT[d][tg * 4];
            s[0][0] += a.x * kv.x; s[0][1] += a.x * kv.y; s[0][2] += a.x * kv.z; s[0][3] += a.x * kv.w;
            s[1][0] += a.y * kv.x; s[1][1] += a.y * kv.y; s[1][2] += a.y * kv.z; s[1][3] += a.y * kv.w;
        }

        // scale + position bias (note transposed semantics: diff = query_x[k] - key_x[q])
        float p[2][4];
#pragma unroll
        for (int i = 0; i < 2; ++i) {
            float kxv = kxq[qg * 2 + i], kyv = kyq[qg * 2 + i];
#pragma unroll
            for (int j = 0; j < 4; ++j) {
                float dx = qxk[tg * 4 + j] - kxv;
                float dy = qyk[tg * 4 + j] - kyv;
                int ix = (int)rintf((fminf(fmaxf(dx, -1000.f), 1000.f) + 1000.f) * 20.f);
                int iy = (int)rintf((fminf(fmaxf(dy, -1000.f), 1000.f) + 1000.f) * 20.f);
                float t2 = xproj[ix * 16 + h] + yproj[iy * 16 + h] + bbv;
                float bias = 1.f / (1.f + expf(-t2));
                s[i][j] = s[i][j] * 0.125f + bias;
            }
        }

        // online softmax update (row group = 16 lanes sharing qg, all in one wave)
#pragma unroll
        for (int i = 0; i < 2; ++i) {
            float mc = fmaxf(fmaxf(s[i][0], s[i][1]), fmaxf(s[i][2], s[i][3]));
#pragma unroll
            for (int o = 8; o >= 1; o >>= 1) mc = fmaxf(mc, __shfl_xor(mc, o));
            float mnew = fmaxf(mrun[i], mc);
            float rsum = 0.f;
#pragma unroll
            for (int j = 0; j < 4; ++j) { p[i][j] = expf(s[i][j] - mnew); rsum += p[i][j]; }
#pragma unroll
            for (int o = 8; o >= 1; o >>= 1) rsum += __shfl_xor(rsum, o);
            float scale = expf(mrun[i] - mnew);
            lsum[i] = lsum[i] * scale + rsum;
            mrun[i] = mnew;
#pragma unroll
            for (int j = 0; j < 4; ++j) acc[i][j] *= scale;
        }
        // write probabilities transposed for PV
#pragma unroll
        for (int j = 0; j < 4; ++j) {
            float2 w; w.x = p[0][j]; w.y = p[1][j];
            *(float2*)&pT[tg * 4 + j][qg * 2] = w;
        }
        __syncthreads();

        // PV: acc[q 2][d 4] += p[q][k] * V[k][d]
#pragma unroll 16
        for (int k = 0; k < 64; ++k) {
            float2 pv = *(const float2*)&pT[k][qg * 2];
            float4 vv = *(const float4*)&vsh[k][tg * 4];
            acc[0][0] += pv.x * vv.x; acc[0][1] += pv.x * vv.y; acc[0][2] += pv.x * vv.z; acc[0][3] += pv.x * vv.w;
            acc[1][0] += pv.y * vv.x; acc[1][1] += pv.y * vv.y; acc[1][2] += pv.y * vv.z; acc[1][3] += pv.y * vv.w;
        }
    }

    // normalize + write (B, NQ, H*64) for the output projection
#pragma unroll
    for (int i = 0; i < 2; ++i) {
        float inv = 1.f / lsum[i];
        int q = q0 + qg * 2 + i;
        float4 o;
        o.x = acc[i][0] * inv; o.y = acc[i][1] * inv;
        o.z = acc[i][2] * inv; o.w = acc[i][3] * inv;
        *(float4*)(attb + (b * NQS + q) * DM + h * DK + tg * 4) = o;
    }
}

// ---------------------------------------------------------------------------
extern "C" void kernel_launch(void* const* d_in, const int* in_sizes, int n_in,
                              void* d_out, int out_size, void* d_ws, size_t ws_size,
                              hipStream_t stream)
{
    const float* query = (const float*)d_in[0];
    const float* key   = (const float*)d_in[1];
    const float* value = (const float*)d_in[2];
    const float* qx    = (const float*)d_in[3];
    const float* qy    = (const float*)d_in[4];
    const float* kx    = (const float*)d_in[5];
    const float* ky    = (const float*)d_in[6];
    const float* Wq    = (const float*)d_in[7];
    const float* bq    = (const float*)d_in[8];
    const float* Wk    = (const float*)d_in[9];
    const float* bk    = (const float*)d_in[10];
    const float* Wv    = (const float*)d_in[11];
    const float* bv    = (const float*)d_in[12];
    const float* Wo    = (const float*)d_in[13];
    const float* bo    = (const float*)d_in[14];
    const float* xt    = (const float*)d_in[15];
    const float* yt    = (const float*)d_in[16];
    const float* Wb    = (const float*)d_in[17];
    const float* bbp   = (const float*)d_in[18];
    float* out = (float*)d_out;

    float* ws = (float*)d_ws;
    float* xproj = ws;                    // 640016 (padded to 640064)
    float* yproj = xproj + 640064;
    float* qbuf  = yproj + 640064;        // (B,H,512,64)
    float* kbufT = qbuf + 1048576;        // (B,H,64,512)
    float* vbuf  = kbufT + 1048576;       // (B,H,512,64)
    float* attb  = vbuf + 1048576;        // (B,512,1024)

    proj_tables_k<<<dim3((2 * NE * HH + 255) / 256), dim3(256), 0, stream>>>(
        xt, yt, Wb, xproj, yproj);
    gemm_k<<<dim3(16, 16, 3), dim3(256), 0, stream>>>(
        query, key, value, Wq, Wk, Wv, bq, bk, bv, qbuf, kbufT, vbuf, 1);
    attn_k<<<dim3(16, 16, 2), dim3(256), 0, stream>>>(
        qbuf, kbufT, vbuf, xproj, yproj, qx, qy, kx, ky, bbp, attb);
    gemm_k<<<dim3(16, 16, 1), dim3(256), 0, stream>>>(
        attb, attb, attb, Wo, Wo, Wo, bo, bo, bo, out, out, out, 0);
}

// Round 2
// 147.342 us; speedup vs baseline: 1.6997x; 1.6997x over previous
//
#include <hip/hip_runtime.h>
#include <math.h>

#define HH 16
#define DM 1024
#define DK 64
#define NE 40001
#define NB 2
#define NQS 512
#define NKS 512

typedef unsigned short ushort_t;
typedef __attribute__((ext_vector_type(8))) short short8v;
typedef __attribute__((ext_vector_type(4))) float f32x4;

__device__ __forceinline__ ushort_t f2bf(float f) {
    union { float f; unsigned u; } v; v.f = f;
    unsigned r = v.u + 0x7FFFu + ((v.u >> 16) & 1u);
    return (ushort_t)(r >> 16);
}
__device__ __forceinline__ unsigned pack2(float a, float b) {
    return (unsigned)f2bf(a) | ((unsigned)f2bf(b) << 16);
}
__device__ __forceinline__ float asf(unsigned u) {
    union { unsigned u; float f; } v; v.u = u; return v.f;
}

// ---------------------------------------------------------------------------
// Kernel 0: fp32 -> bf16 converts. z<3: copy-convert query/key/value.
// z>=3: transpose-convert W (row-major [K][N] fp32 -> [N][K] bf16).
// ---------------------------------------------------------------------------
__global__ __launch_bounds__(256) void cvt_k(
    const float* __restrict__ xq, const float* __restrict__ xk, const float* __restrict__ xv,
    const float* __restrict__ wq, const float* __restrict__ wk,
    const float* __restrict__ wv, const float* __restrict__ wo,
    ushort_t* __restrict__ qc, ushort_t* __restrict__ kc, ushort_t* __restrict__ vc,
    ushort_t* __restrict__ wqt, ushort_t* __restrict__ wkt,
    ushort_t* __restrict__ wvt, ushort_t* __restrict__ wot)
{
    const int z = blockIdx.z;
    const int t = blockIdx.x * 256 + threadIdx.x;   // 0..131071
    if (z < 3) {
        const float* src = (z == 0) ? xq : ((z == 1) ? xk : xv);
        ushort_t* dst = (z == 0) ? qc : ((z == 1) ? kc : vc);
        float4 a = ((const float4*)src)[t * 2];
        float4 b = ((const float4*)src)[t * 2 + 1];
        uint4 o;
        o.x = pack2(a.x, a.y); o.y = pack2(a.z, a.w);
        o.z = pack2(b.x, b.y); o.w = pack2(b.z, b.w);
        *reinterpret_cast<uint4*>(dst + t * 8) = o;
    } else {
        const float* w = (z == 3) ? wq : ((z == 4) ? wk : ((z == 5) ? wv : wo));
        ushort_t* wt = (z == 3) ? wqt : ((z == 4) ? wkt : ((z == 5) ? wvt : wot));
        const int n = t & 1023;
        const int k0 = (t >> 10) << 3;
        float e[8];
#pragma unroll
        for (int j = 0; j < 8; ++j) e[j] = w[(k0 + j) * 1024 + n];
        uint4 o;
        o.x = pack2(e[0], e[1]); o.y = pack2(e[2], e[3]);
        o.z = pack2(e[4], e[5]); o.w = pack2(e[6], e[7]);
        *reinterpret_cast<uint4*>(wt + n * 1024 + k0) = o;
    }
}

// ---------------------------------------------------------------------------
// Kernel 1: project embedding tables through Wb (shared across heads):
//   xproj[i][h] = sum_d x_table[i, h*16+d] * Wb[d]
// ---------------------------------------------------------------------------
__global__ __launch_bounds__(256) void proj_tables_k(
    const float* __restrict__ xt, const float* __restrict__ yt,
    const float* __restrict__ Wb,
    float* __restrict__ xproj, float* __restrict__ yproj)
{
    int gid = blockIdx.x * 256 + threadIdx.x;
    const int tot = NE * HH;            // 640016
    if (gid >= 2 * tot) return;
    const float* tab = xt;
    float* dst = xproj;
    int r = gid;
    if (r >= tot) { r -= tot; tab = yt; dst = yproj; }
    int i = r >> 4, h = r & 15;
    const float* p = tab + i * 256 + h * 16;
    float s = 0.f;
#pragma unroll
    for (int d = 0; d < 16; ++d) s += p[d] * Wb[d];
    dst[r] = s;
}

// ---------------------------------------------------------------------------
// Kernel 2: bias precompute. One thread per (b,q,k): gather the two 16-float
// projected rows ONCE, emit sigmoid for all 16 heads as bf16.
// Layout (b,h,q,k) so attention reads are coalesced.
// Transposed semantics (matches ref): diff = query_pos[k] - key_pos[q].
// ---------------------------------------------------------------------------
__global__ __launch_bounds__(256) void bias_k(
    const float* __restrict__ xproj, const float* __restrict__ yproj,
    const float* __restrict__ qx, const float* __restrict__ qy,
    const float* __restrict__ kx, const float* __restrict__ ky,
    const float* __restrict__ bbp,
    ushort_t* __restrict__ biasb)
{
    const int k = blockIdx.x * 256 + threadIdx.x;   // 0..511
    const int q = blockIdx.y;
    const int b = blockIdx.z;
    float dx = qx[b * NKS + k] - kx[b * NQS + q];
    float dy = qy[b * NKS + k] - ky[b * NQS + q];
    int ix = (int)rintf((fminf(fmaxf(dx, -1000.f), 1000.f) + 1000.f) * 20.f);
    int iy = (int)rintf((fminf(fmaxf(dy, -1000.f), 1000.f) + 1000.f) * 20.f);
    const float bb = bbp[0];
    const float4* xr = (const float4*)(xproj + ix * 16);
    const float4* yr = (const float4*)(yproj + iy * 16);
    const long base = ((long)(b * HH) * NQS + q) * NKS + k;
#pragma unroll
    for (int c = 0; c < 4; ++c) {
        float4 xv = xr[c], yv = yr[c];
        float t0 = xv.x + yv.x + bb, t1 = xv.y + yv.y + bb;
        float t2 = xv.z + yv.z + bb, t3 = xv.w + yv.w + bb;
        biasb[base + (long)(c * 4 + 0) * NQS * NKS] = f2bf(1.f / (1.f + __expf(-t0)));
        biasb[base + (long)(c * 4 + 1) * NQS * NKS] = f2bf(1.f / (1.f + __expf(-t1)));
        biasb[base + (long)(c * 4 + 2) * NQS * NKS] = f2bf(1.f / (1.f + __expf(-t2)));
        biasb[base + (long)(c * 4 + 3) * NQS * NKS] = f2bf(1.f / (1.f + __expf(-t3)));
    }
}

// ---------------------------------------------------------------------------
// Kernel 3: bf16 MFMA GEMM, 64x64 tile, BK=32, 4 waves of 32x32.
// A: [M][1024] bf16 row-major. B: [N][1024] bf16 (pre-transposed W).
// EPI=1: z in {0,1,2} -> QKV scatter epilogue (fp32). EPI=0: plain [M][N] fp32.
// ---------------------------------------------------------------------------
template<int EPI>
__global__ __launch_bounds__(256) void gemm_bf16_k(
    const ushort_t* __restrict__ A0, const ushort_t* __restrict__ A1, const ushort_t* __restrict__ A2,
    const ushort_t* __restrict__ B0, const ushort_t* __restrict__ B1, const ushort_t* __restrict__ B2,
    const float* __restrict__ bi0, const float* __restrict__ bi1, const float* __restrict__ bi2,
    float* __restrict__ Y0, float* __restrict__ Y1, float* __restrict__ Y2)
{
    __shared__ ushort_t As[64][40];
    __shared__ ushort_t Bs[64][40];
    const int z = blockIdx.z;
    const ushort_t* A = (z == 0) ? A0 : ((z == 1) ? A1 : A2);
    const ushort_t* B = (z == 0) ? B0 : ((z == 1) ? B1 : B2);
    const float* bi = (z == 0) ? bi0 : ((z == 1) ? bi1 : bi2);
    float* Y = (z == 0) ? Y0 : ((z == 1) ? Y1 : Y2);
    const int m0 = blockIdx.y * 64, n0 = blockIdx.x * 64;
    const int tid = threadIdx.x;
    const int lane = tid & 63, w = tid >> 6;
    const int wm = w >> 1, wn = w & 1;
    const int sr = tid >> 2, sc = (tid & 3) * 8;

    f32x4 acc[2][2] = {};
    short8v ar = *(const short8v*)(A + (m0 + sr) * 1024 + sc);
    short8v br = *(const short8v*)(B + (n0 + sr) * 1024 + sc);

    const int fr = lane & 15;            // frag row/col within 16
    const int ko = (lane >> 4) * 8;      // k offset within 32

    for (int k0 = 0; k0 < 1024; k0 += 32) {
        __syncthreads();
        *reinterpret_cast<short8v*>(&As[sr][sc]) = ar;
        *reinterpret_cast<short8v*>(&Bs[sr][sc]) = br;
        __syncthreads();
        if (k0 + 32 < 1024) {
            ar = *(const short8v*)(A + (m0 + sr) * 1024 + k0 + 32 + sc);
            br = *(const short8v*)(B + (n0 + sr) * 1024 + k0 + 32 + sc);
        }
        short8v af0 = *(const short8v*)&As[wm * 32 + fr][ko];
        short8v af1 = *(const short8v*)&As[wm * 32 + 16 + fr][ko];
        short8v bf0 = *(const short8v*)&Bs[wn * 32 + fr][ko];
        short8v bf1 = *(const short8v*)&Bs[wn * 32 + 16 + fr][ko];
        acc[0][0] = __builtin_amdgcn_mfma_f32_16x16x32_bf16(af0, bf0, acc[0][0], 0, 0, 0);
        acc[0][1] = __builtin_amdgcn_mfma_f32_16x16x32_bf16(af0, bf1, acc[0][1], 0, 0, 0);
        acc[1][0] = __builtin_amdgcn_mfma_f32_16x16x32_bf16(af1, bf0, acc[1][0], 0, 0, 0);
        acc[1][1] = __builtin_amdgcn_mfma_f32_16x16x32_bf16(af1, bf1, acc[1][1], 0, 0, 0);
    }

    const int cr = (lane >> 4) * 4;      // C row base (+reg j)
    const int cc = lane & 15;            // C col
#pragma unroll
    for (int m = 0; m < 2; ++m) {
#pragma unroll
        for (int n = 0; n < 2; ++n) {
            int grow = m0 + wm * 32 + m * 16 + cr;
            int gcol = n0 + wn * 32 + n * 16 + cc;
            float bv = bi[gcol];
            if (EPI == 0) {
#pragma unroll
                for (int j = 0; j < 4; ++j)
                    Y[(grow + j) * 1024 + gcol] = acc[m][n][j] + bv;
            } else {
                int hh = gcol >> 6, dd = gcol & 63;
                if (z != 1) {
#pragma unroll
                    for (int j = 0; j < 4; ++j) {
                        int r = grow + j, bb_ = r >> 9, nn = r & 511;
                        Y[((bb_ * HH + hh) * NQS + nn) * DK + dd] = acc[m][n][j] + bv;
                    }
                } else {
#pragma unroll
                    for (int j = 0; j < 4; ++j) {
                        int r = grow + j, bb_ = r >> 9, nn = r & 511;
                        Y[((bb_ * HH + hh) * DK + dd) * NKS + nn] = acc[m][n][j] + bv;
                    }
                }
            }
        }
    }
}

// ---------------------------------------------------------------------------
// Kernel 4: fused attention, flash-style online softmax.
// q-tile 16 (grid 32x16x2 = 1024 blocks), k-chunk 64, K/V staged bf16 in LDS.
// Thread (qg=tid>>4, tg=tid&15): one q row, 4 k cols / 4 d cols.
// Bias read from precomputed bf16 buffer. Output written bf16 for O-GEMM.
// ---------------------------------------------------------------------------
__global__ __launch_bounds__(256) void attn_k(
    const float* __restrict__ qbuf, const float* __restrict__ kbufT, const float* __restrict__ vbuf,
    const ushort_t* __restrict__ biasb,
    ushort_t* __restrict__ attb)
{
    __shared__ float qsT[64][20];      // [d][q]
    __shared__ ushort_t kTh[64][72];   // [d][k-chunk] bf16
    __shared__ ushort_t vshh[64][72];  // [k-chunk][d] bf16
    __shared__ float pT[64][18];       // [k-chunk][q]

    const int tid = threadIdx.x;
    const int q0 = blockIdx.x * 16;
    const int h = blockIdx.y, b = blockIdx.z;
    const int bh = b * HH + h;
    const int qg = tid >> 4, tg = tid & 15;

    {   // stage Q (fp32): 16 q x 64 d
        int q = tid >> 4, c = (tid & 15) * 4;
        float4 v = *(const float4*)(qbuf + (bh * NQS + q0 + q) * DK + c);
        qsT[c + 0][q] = v.x; qsT[c + 1][q] = v.y; qsT[c + 2][q] = v.z; qsT[c + 3][q] = v.w;
    }

    float acc[4] = {0.f, 0.f, 0.f, 0.f};
    float mrun = -1e30f, lsum = 0.f;
    const ushort_t* brow = biasb + ((long)bh * NQS + q0 + qg) * NKS;

    for (int kc = 0; kc < NKS; kc += 64) {
        __syncthreads();
#pragma unroll
        for (int half = 0; half < 2; ++half) {
            int idx = tid + half * 256;
            int d = idx >> 3, c = (idx & 7) * 8;
            float4 ka = *(const float4*)(kbufT + (bh * DK + d) * NKS + kc + c);
            float4 kb4 = *(const float4*)(kbufT + (bh * DK + d) * NKS + kc + c + 4);
            uint4 kp;
            kp.x = pack2(ka.x, ka.y); kp.y = pack2(ka.z, ka.w);
            kp.z = pack2(kb4.x, kb4.y); kp.w = pack2(kb4.z, kb4.w);
            *reinterpret_cast<uint4*>(&kTh[d][c]) = kp;
            float4 va = *(const float4*)(vbuf + (bh * NKS + kc + d) * DK + c);
            float4 vb4 = *(const float4*)(vbuf + (bh * NKS + kc + d) * DK + c + 4);
            uint4 vp;
            vp.x = pack2(va.x, va.y); vp.y = pack2(va.z, va.w);
            vp.z = pack2(vb4.x, vb4.y); vp.w = pack2(vb4.z, vb4.w);
            *reinterpret_cast<uint4*>(&vshh[d][c]) = vp;
        }
        __syncthreads();

        float s[4] = {0.f, 0.f, 0.f, 0.f};
#pragma unroll 8
        for (int d = 0; d < 64; ++d) {
            float a = qsT[d][qg];
            uint2 kv = *(const uint2*)&kTh[d][tg * 4];
            s[0] += a * asf(kv.x << 16);
            s[1] += a * asf(kv.x & 0xFFFF0000u);
            s[2] += a * asf(kv.y << 16);
            s[3] += a * asf(kv.y & 0xFFFF0000u);
        }

        // scale + precomputed bias
        uint2 bw = *(const uint2*)(brow + kc + tg * 4);
        s[0] = s[0] * 0.125f + asf(bw.x << 16);
        s[1] = s[1] * 0.125f + asf(bw.x & 0xFFFF0000u);
        s[2] = s[2] * 0.125f + asf(bw.y << 16);
        s[3] = s[3] * 0.125f + asf(bw.y & 0xFFFF0000u);

        // online softmax over the 16-lane row group
        float mc = fmaxf(fmaxf(s[0], s[1]), fmaxf(s[2], s[3]));
#pragma unroll
        for (int o = 8; o >= 1; o >>= 1) mc = fmaxf(mc, __shfl_xor(mc, o));
        float mnew = fmaxf(mrun, mc);
        float p[4], rsum = 0.f;
#pragma unroll
        for (int j = 0; j < 4; ++j) { p[j] = __expf(s[j] - mnew); rsum += p[j]; }
#pragma unroll
        for (int o = 8; o >= 1; o >>= 1) rsum += __shfl_xor(rsum, o);
        float scale = __expf(mrun - mnew);
        lsum = lsum * scale + rsum;
        mrun = mnew;
#pragma unroll
        for (int j = 0; j < 4; ++j) acc[j] *= scale;

#pragma unroll
        for (int j = 0; j < 4; ++j) pT[tg * 4 + j][qg] = p[j];
        __syncthreads();

#pragma unroll 8
        for (int k = 0; k < 64; ++k) {
            float pv = pT[k][qg];
            uint2 vv = *(const uint2*)&vshh[k][tg * 4];
            acc[0] += pv * asf(vv.x << 16);
            acc[1] += pv * asf(vv.x & 0xFFFF0000u);
            acc[2] += pv * asf(vv.y << 16);
            acc[3] += pv * asf(vv.y & 0xFFFF0000u);
        }
    }

    float inv = 1.f / lsum;
    int q = q0 + qg;
    uint2 o;
    o.x = pack2(acc[0] * inv, acc[1] * inv);
    o.y = pack2(acc[2] * inv, acc[3] * inv);
    *reinterpret_cast<uint2*>(attb + (b * NQS + q) * DM + h * DK + tg * 4) = o;
}

// ---------------------------------------------------------------------------
extern "C" void kernel_launch(void* const* d_in, const int* in_sizes, int n_in,
                              void* d_out, int out_size, void* d_ws, size_t ws_size,
                              hipStream_t stream)
{
    const float* query = (const float*)d_in[0];
    const float* key   = (const float*)d_in[1];
    const float* value = (const float*)d_in[2];
    const float* qx    = (const float*)d_in[3];
    const float* qy    = (const float*)d_in[4];
    const float* kx    = (const float*)d_in[5];
    const float* ky    = (const float*)d_in[6];
    const float* Wq    = (const float*)d_in[7];
    const float* bq    = (const float*)d_in[8];
    const float* Wk    = (const float*)d_in[9];
    const float* bk    = (const float*)d_in[10];
    const float* Wv    = (const float*)d_in[11];
    const float* bv    = (const float*)d_in[12];
    const float* Wo    = (const float*)d_in[13];
    const float* bo    = (const float*)d_in[14];
    const float* xt    = (const float*)d_in[15];
    const float* yt    = (const float*)d_in[16];
    const float* Wb    = (const float*)d_in[17];
    const float* bbp   = (const float*)d_in[18];
    float* out = (float*)d_out;

    float* ws = (float*)d_ws;
    float* xproj = ws;                                   // 640064
    float* yproj = xproj + 640064;                       // 640064
    ushort_t* biasb = (ushort_t*)(yproj + 640064);       // 8388608 bf16 = 4194304 f32 slots
    float* qbuf  = yproj + 640064 + 4194304;             // 1048576 f32
    float* kbufT = qbuf + 1048576;                       // 1048576
    float* vbuf  = kbufT + 1048576;                      // 1048576
    ushort_t* attb = (ushort_t*)(vbuf + 1048576);        // 1048576 bf16 = 524288 slots
    float* p = vbuf + 1048576 + 524288;
    ushort_t* qc  = (ushort_t*)p;                        // each 1048576 bf16 = 524288 slots
    ushort_t* kcb = (ushort_t*)(p + 524288);
    ushort_t* vcb = (ushort_t*)(p + 2 * 524288);
    ushort_t* wqt = (ushort_t*)(p + 3 * 524288);
    ushort_t* wkt = (ushort_t*)(p + 4 * 524288);
    ushort_t* wvt = (ushort_t*)(p + 5 * 524288);
    ushort_t* wot = (ushort_t*)(p + 6 * 524288);

    cvt_k<<<dim3(512, 1, 7), dim3(256), 0, stream>>>(
        query, key, value, Wq, Wk, Wv, Wo, qc, kcb, vcb, wqt, wkt, wvt, wot);
    proj_tables_k<<<dim3((2 * NE * HH + 255) / 256), dim3(256), 0, stream>>>(
        xt, yt, Wb, xproj, yproj);
    bias_k<<<dim3(2, 512, 2), dim3(256), 0, stream>>>(
        xproj, yproj, qx, qy, kx, ky, bbp, biasb);
    gemm_bf16_k<1><<<dim3(16, 16, 3), dim3(256), 0, stream>>>(
        qc, kcb, vcb, wqt, wkt, wvt, bq, bk, bv, qbuf, kbufT, vbuf);
    attn_k<<<dim3(32, 16, 2), dim3(256), 0, stream>>>(
        qbuf, kbufT, vbuf, biasb, attb);
    gemm_bf16_k<0><<<dim3(16, 16, 1), dim3(256), 0, stream>>>(
        attb, attb, attb, wot, wot, wot, bo, bo, bo, out, out, out);
}

// Round 3
// 96.211 us; speedup vs baseline: 2.6030x; 1.5315x over previous
//
#include <hip/hip_runtime.h>
#include <math.h>

#define HH 16
#define DM 1024
#define DK 64
#define NE 40001
#define NB 2
#define NQS 512
#define NKS 512

typedef unsigned short ushort_t;
typedef __attribute__((ext_vector_type(8))) short short8v;
typedef __attribute__((ext_vector_type(4))) float f32x4;

__device__ __forceinline__ ushort_t f2bf(float f) {
    union { float f; unsigned u; } v; v.f = f;
    unsigned r = v.u + 0x7FFFu + ((v.u >> 16) & 1u);
    return (ushort_t)(r >> 16);
}
__device__ __forceinline__ unsigned pack2(float a, float b) {
    return (unsigned)f2bf(a) | ((unsigned)f2bf(b) << 16);
}
__device__ __forceinline__ float asf(unsigned u) {
    union { unsigned u; float f; } v; v.u = u; return v.f;
}

// ---------------------------------------------------------------------------
// Kernel 0: fp32 -> bf16 converts. z<3: copy-convert query/key/value.
// z>=3: transpose-convert W (row-major [K][N] fp32 -> [N][K] bf16).
// ---------------------------------------------------------------------------
__global__ __launch_bounds__(256) void cvt_k(
    const float* __restrict__ xq, const float* __restrict__ xk, const float* __restrict__ xv,
    const float* __restrict__ wq, const float* __restrict__ wk,
    const float* __restrict__ wv, const float* __restrict__ wo,
    ushort_t* __restrict__ qc, ushort_t* __restrict__ kc, ushort_t* __restrict__ vc,
    ushort_t* __restrict__ wqt, ushort_t* __restrict__ wkt,
    ushort_t* __restrict__ wvt, ushort_t* __restrict__ wot)
{
    const int z = blockIdx.z;
    const int t = blockIdx.x * 256 + threadIdx.x;   // 0..131071
    if (z < 3) {
        const float* src = (z == 0) ? xq : ((z == 1) ? xk : xv);
        ushort_t* dst = (z == 0) ? qc : ((z == 1) ? kc : vc);
        float4 a = ((const float4*)src)[t * 2];
        float4 b = ((const float4*)src)[t * 2 + 1];
        uint4 o;
        o.x = pack2(a.x, a.y); o.y = pack2(a.z, a.w);
        o.z = pack2(b.x, b.y); o.w = pack2(b.z, b.w);
        *reinterpret_cast<uint4*>(dst + t * 8) = o;
    } else {
        const float* w = (z == 3) ? wq : ((z == 4) ? wk : ((z == 5) ? wv : wo));
        ushort_t* wt = (z == 3) ? wqt : ((z == 4) ? wkt : ((z == 5) ? wvt : wot));
        const int n = t & 1023;
        const int k0 = (t >> 10) << 3;
        float e[8];
#pragma unroll
        for (int j = 0; j < 8; ++j) e[j] = w[(k0 + j) * 1024 + n];
        uint4 o;
        o.x = pack2(e[0], e[1]); o.y = pack2(e[2], e[3]);
        o.z = pack2(e[4], e[5]); o.w = pack2(e[6], e[7]);
        *reinterpret_cast<uint4*>(wt + n * 1024 + k0) = o;
    }
}

// ---------------------------------------------------------------------------
// Kernel 1: project embedding tables through Wb (shared across heads):
//   xproj[i][h] = sum_d x_table[i, h*16+d] * Wb[d]
// ---------------------------------------------------------------------------
__global__ __launch_bounds__(256) void proj_tables_k(
    const float* __restrict__ xt, const float* __restrict__ yt,
    const float* __restrict__ Wb,
    float* __restrict__ xproj, float* __restrict__ yproj)
{
    int gid = blockIdx.x * 256 + threadIdx.x;
    const int tot = NE * HH;            // 640016
    if (gid >= 2 * tot) return;
    const float* tab = xt;
    float* dst = xproj;
    int r = gid;
    if (r >= tot) { r -= tot; tab = yt; dst = yproj; }
    int i = r >> 4, h = r & 15;
    const float* p = tab + i * 256 + h * 16;
    float s = 0.f;
#pragma unroll
    for (int d = 0; d < 16; ++d) s += p[d] * Wb[d];
    dst[r] = s;
}

// ---------------------------------------------------------------------------
// Kernel 2: bias precompute in MFMA-fragment layout.
// Block = one 16x16 (qt,kt) tile of the score matrix for all 16 heads.
// Thread t -> (qlocal = t&15, klocal = t>>4); gathers the two 16-float
// projected rows ONCE (shared by all heads), writes bf16 sigmoid values at
//   biasf[(((bh*32 + kt)*32 + qt) << 8) + lane*4 + j]
// where lane = (klocal>>2)*16 + qlocal, j = klocal&3 — exactly the C-frag
// position of the swapped (S^T) MFMA in attn_k.
// Transposed semantics (matches ref): diff = query_pos[k] - key_pos[q].
// ---------------------------------------------------------------------------
__global__ __launch_bounds__(256) void bias_k(
    const float* __restrict__ xproj, const float* __restrict__ yproj,
    const float* __restrict__ qx, const float* __restrict__ qy,
    const float* __restrict__ kx, const float* __restrict__ ky,
    const float* __restrict__ bbp,
    ushort_t* __restrict__ biasf)
{
    const int t = threadIdx.x;
    const int qt = blockIdx.x, kt = blockIdx.y, b = blockIdx.z;
    const int ql = t & 15, kl = t >> 4;
    const int qg = qt * 16 + ql, kg = kt * 16 + kl;

    float dx = qx[b * NKS + kg] - kx[b * NQS + qg];
    float dy = qy[b * NKS + kg] - ky[b * NQS + qg];
    int ix = (int)rintf((fminf(fmaxf(dx, -1000.f), 1000.f) + 1000.f) * 20.f);
    int iy = (int)rintf((fminf(fmaxf(dy, -1000.f), 1000.f) + 1000.f) * 20.f);
    const float bb = bbp[0];

    const float4* xr = (const float4*)(xproj + ix * 16);
    const float4* yr = (const float4*)(yproj + iy * 16);
    float xa[16], ya[16];
#pragma unroll
    for (int c = 0; c < 4; ++c) {
        float4 xv = xr[c], yv = yr[c];
        xa[c * 4 + 0] = xv.x; xa[c * 4 + 1] = xv.y; xa[c * 4 + 2] = xv.z; xa[c * 4 + 3] = xv.w;
        ya[c * 4 + 0] = yv.x; ya[c * 4 + 1] = yv.y; ya[c * 4 + 2] = yv.z; ya[c * 4 + 3] = yv.w;
    }
    const int lane_j = ((kl >> 2) * 16 + ql) * 4 + (kl & 3);
    const int tile_stride = 32 * 32 * 256;
#pragma unroll
    for (int h = 0; h < HH; ++h) {
        float t2 = xa[h] + ya[h] + bb;
        float sig = 1.f / (1.f + __expf(-t2));
        biasf[((b * HH + h) * 32 + kt) * (32 * 256) + qt * 256 + lane_j] = f2bf(sig);
    }
    (void)tile_stride;
}

// ---------------------------------------------------------------------------
// Kernel 3: bf16 MFMA GEMM, 64x64 tile, BK=32, 4 waves of 32x32.
// A: [M][1024] bf16 row-major. B: [N][1024] bf16 (pre-transposed W).
// EPI=1: z in {0,1,2} -> Q,K (B,H,N,64) bf16 ; V (B,H,64,N) bf16 transposed.
// EPI=0: plain [M][N] fp32 (the output projection).
// ---------------------------------------------------------------------------
template<int EPI>
__global__ __launch_bounds__(256) void gemm_bf16_k(
    const ushort_t* __restrict__ A0, const ushort_t* __restrict__ A1, const ushort_t* __restrict__ A2,
    const ushort_t* __restrict__ B0, const ushort_t* __restrict__ B1, const ushort_t* __restrict__ B2,
    const float* __restrict__ bi0, const float* __restrict__ bi1, const float* __restrict__ bi2,
    ushort_t* __restrict__ Yh0, ushort_t* __restrict__ Yh1, ushort_t* __restrict__ Yh2,
    float* __restrict__ Yf)
{
    __shared__ ushort_t As[64][40];
    __shared__ ushort_t Bs[64][40];
    const int z = blockIdx.z;
    const ushort_t* A = (z == 0) ? A0 : ((z == 1) ? A1 : A2);
    const ushort_t* B = (z == 0) ? B0 : ((z == 1) ? B1 : B2);
    const float* bi = (z == 0) ? bi0 : ((z == 1) ? bi1 : bi2);
    ushort_t* Yh = (z == 0) ? Yh0 : ((z == 1) ? Yh1 : Yh2);
    const int m0 = blockIdx.y * 64, n0 = blockIdx.x * 64;
    const int tid = threadIdx.x;
    const int lane = tid & 63, w = tid >> 6;
    const int wm = w >> 1, wn = w & 1;
    const int sr = tid >> 2, sc = (tid & 3) * 8;

    f32x4 acc[2][2] = {};
    short8v ar = *(const short8v*)(A + (m0 + sr) * 1024 + sc);
    short8v br = *(const short8v*)(B + (n0 + sr) * 1024 + sc);

    const int fr = lane & 15;            // frag row/col within 16
    const int ko = (lane >> 4) * 8;      // k offset within 32

    for (int k0 = 0; k0 < 1024; k0 += 32) {
        __syncthreads();
        *reinterpret_cast<short8v*>(&As[sr][sc]) = ar;
        *reinterpret_cast<short8v*>(&Bs[sr][sc]) = br;
        __syncthreads();
        if (k0 + 32 < 1024) {
            ar = *(const short8v*)(A + (m0 + sr) * 1024 + k0 + 32 + sc);
            br = *(const short8v*)(B + (n0 + sr) * 1024 + k0 + 32 + sc);
        }
        short8v af0 = *(const short8v*)&As[wm * 32 + fr][ko];
        short8v af1 = *(const short8v*)&As[wm * 32 + 16 + fr][ko];
        short8v bf0 = *(const short8v*)&Bs[wn * 32 + fr][ko];
        short8v bf1 = *(const short8v*)&Bs[wn * 32 + 16 + fr][ko];
        acc[0][0] = __builtin_amdgcn_mfma_f32_16x16x32_bf16(af0, bf0, acc[0][0], 0, 0, 0);
        acc[0][1] = __builtin_amdgcn_mfma_f32_16x16x32_bf16(af0, bf1, acc[0][1], 0, 0, 0);
        acc[1][0] = __builtin_amdgcn_mfma_f32_16x16x32_bf16(af1, bf0, acc[1][0], 0, 0, 0);
        acc[1][1] = __builtin_amdgcn_mfma_f32_16x16x32_bf16(af1, bf1, acc[1][1], 0, 0, 0);
    }

    const int cr = (lane >> 4) * 4;      // C row base (+reg j)
    const int cc = lane & 15;            // C col
#pragma unroll
    for (int m = 0; m < 2; ++m) {
#pragma unroll
        for (int n = 0; n < 2; ++n) {
            int grow = m0 + wm * 32 + m * 16 + cr;
            int gcol = n0 + wn * 32 + n * 16 + cc;
            float bv = bi[gcol];
            if (EPI == 0) {
#pragma unroll
                for (int j = 0; j < 4; ++j)
                    Yf[(grow + j) * 1024 + gcol] = acc[m][n][j] + bv;
            } else {
                int hh = gcol >> 6, dd = gcol & 63;
                if (z != 2) {
                    // Q,K: (B,H,N,64) bf16
#pragma unroll
                    for (int j = 0; j < 4; ++j) {
                        int r = grow + j, bb_ = r >> 9, nn = r & 511;
                        Yh[((bb_ * HH + hh) * NQS + nn) * DK + dd] = f2bf(acc[m][n][j] + bv);
                    }
                } else {
                    // V: (B,H,64,N) bf16 transposed
#pragma unroll
                    for (int j = 0; j < 4; ++j) {
                        int r = grow + j, bb_ = r >> 9, nn = r & 511;
                        Yh[((bb_ * HH + hh) * DK + dd) * NKS + nn] = f2bf(acc[m][n][j] + bv);
                    }
                }
            }
        }
    }
}

// ---------------------------------------------------------------------------
// Kernel 4: MFMA flash attention, swapped operands.
// Grid (32 qtiles, 16 h, 2 b); 4 waves, each wave handles k-range wid*128..+128.
// Per chunk of 32 k:
//   S^T = mfma(K,Q): lane owns column q=lane&15, rows k=16t+4g+j.
//   softmax: lane-local + 2 shfl_xor (g-axis) for row max; l stays per-lane.
//   P^T frag built via per-wave LDS tile (no barrier: same-wave dep).
//   O^T = mfma(V^T, P^T): lane keeps q=lane&15 -> lane-local rescale.
// End: (m,l,O) merged across the 4 waves through LDS (one barrier).
// ---------------------------------------------------------------------------
__global__ __launch_bounds__(256, 4) void attn_k(
    const ushort_t* __restrict__ qbh, const ushort_t* __restrict__ kbh,
    const ushort_t* __restrict__ vtb, const ushort_t* __restrict__ biasf,
    ushort_t* __restrict__ attb)
{
    __shared__ ushort_t pst[4][16][40];     // per-wave P tiles [q][k32] (+pad)
    __shared__ float obuf[4][16][76];       // per-wave O^T partials [q][d]
    __shared__ float mt[4][16], lt[4][16];

    const int tid = threadIdx.x;
    const int wid = tid >> 6, lane = tid & 63;
    const int q = lane & 15, g = lane >> 4;
    const int qt = blockIdx.x;
    const int h = blockIdx.y, b = blockIdx.z;
    const int bh = b * HH + h;

    const ushort_t* Qp = qbh + (bh * NQS + qt * 16 + q) * DK + g * 8;
    short8v qf0 = *(const short8v*)Qp;
    short8v qf1 = *(const short8v*)(Qp + 32);

    f32x4 oacc[4] = {};
    float m = -1e30f, l = 0.f;

#pragma unroll 2
    for (int c = 0; c < 4; ++c) {
        const int kc = wid * 128 + c * 32;
        const ushort_t* Kp = kbh + (bh * NKS + kc + q) * DK + g * 8;
        short8v kf00 = *(const short8v*)(Kp);
        short8v kf01 = *(const short8v*)(Kp + 32);
        short8v kf10 = *(const short8v*)(Kp + 16 * DK);
        short8v kf11 = *(const short8v*)(Kp + 16 * DK + 32);

        f32x4 s0 = {0.f, 0.f, 0.f, 0.f};
        f32x4 s1 = {0.f, 0.f, 0.f, 0.f};
        s0 = __builtin_amdgcn_mfma_f32_16x16x32_bf16(kf00, qf0, s0, 0, 0, 0);
        s0 = __builtin_amdgcn_mfma_f32_16x16x32_bf16(kf01, qf1, s0, 0, 0, 0);
        s1 = __builtin_amdgcn_mfma_f32_16x16x32_bf16(kf10, qf0, s1, 0, 0, 0);
        s1 = __builtin_amdgcn_mfma_f32_16x16x32_bf16(kf11, qf1, s1, 0, 0, 0);

        // bias (fragment layout): tiles kt, kt+1
        const int kt = kc >> 4;
        uint2 b0 = *((const uint2*)(biasf + ((bh * 32 + kt) * 32 + qt) * 256) + lane);
        uint2 b1 = *((const uint2*)(biasf + ((bh * 32 + kt + 1) * 32 + qt) * 256) + lane);

        float sv[8];
        sv[0] = s0[0] * 0.125f + asf(b0.x << 16);
        sv[1] = s0[1] * 0.125f + asf(b0.x & 0xFFFF0000u);
        sv[2] = s0[2] * 0.125f + asf(b0.y << 16);
        sv[3] = s0[3] * 0.125f + asf(b0.y & 0xFFFF0000u);
        sv[4] = s1[0] * 0.125f + asf(b1.x << 16);
        sv[5] = s1[1] * 0.125f + asf(b1.x & 0xFFFF0000u);
        sv[6] = s1[2] * 0.125f + asf(b1.y << 16);
        sv[7] = s1[3] * 0.125f + asf(b1.y & 0xFFFF0000u);

        // row max across this lane's 8 + the 3 other g-lanes of column q
        float mc = fmaxf(fmaxf(fmaxf(sv[0], sv[1]), fmaxf(sv[2], sv[3])),
                         fmaxf(fmaxf(sv[4], sv[5]), fmaxf(sv[6], sv[7])));
        mc = fmaxf(mc, __shfl_xor(mc, 16));
        mc = fmaxf(mc, __shfl_xor(mc, 32));
        float mn = fmaxf(m, mc);

        float p[8], ps = 0.f;
#pragma unroll
        for (int j = 0; j < 8; ++j) { p[j] = __expf(sv[j] - mn); ps += p[j]; }
        float sc = __expf(m - mn);
        l = l * sc + ps;
        m = mn;
#pragma unroll
        for (int dt = 0; dt < 4; ++dt)
#pragma unroll
            for (int j = 0; j < 4; ++j) oacc[dt][j] *= sc;

        // P^T fragment via per-wave LDS tile: write k = 16t + 4g + 2jj (+1)
        ushort_t* prow = &pst[wid][q][0];
        *(unsigned*)(prow + 4 * g)      = pack2(p[0], p[1]);
        *(unsigned*)(prow + 4 * g + 2)  = pack2(p[2], p[3]);
        *(unsigned*)(prow + 16 + 4 * g)     = pack2(p[4], p[5]);
        *(unsigned*)(prow + 16 + 4 * g + 2) = pack2(p[6], p[7]);
        short8v pf = *(const short8v*)&pst[wid][q][8 * g];

        // O^T += V^T . P^T over this chunk's 32 k
        const ushort_t* Vp = vtb + (bh * DK + q) * NKS + kc + g * 8;
#pragma unroll
        for (int dt = 0; dt < 4; ++dt) {
            short8v vf = *(const short8v*)(Vp + dt * 16 * NKS);
            oacc[dt] = __builtin_amdgcn_mfma_f32_16x16x32_bf16(vf, pf, oacc[dt], 0, 0, 0);
        }
    }

    // intra-wave l across the 4 g-lanes of each q (m already shared)
    float lr = l + __shfl_xor(l, 16);
    lr = lr + __shfl_xor(lr, 32);
    if (lane < 16) { mt[wid][lane] = m; lt[wid][lane] = lr; }
#pragma unroll
    for (int dt = 0; dt < 4; ++dt)
#pragma unroll
        for (int j = 0; j < 4; ++j)
            obuf[wid][q][dt * 16 + 4 * g + j] = oacc[dt][j];
    __syncthreads();

    // merge 4 wave-partials: thread -> (q = tid>>4, d4 = (tid&15)*4)
    const int mq = tid >> 4, d4 = (tid & 15) * 4;
    float m0 = mt[0][mq], m1 = mt[1][mq], m2 = mt[2][mq], m3 = mt[3][mq];
    float ms = fmaxf(fmaxf(m0, m1), fmaxf(m2, m3));
    float e0 = __expf(m0 - ms), e1 = __expf(m1 - ms);
    float e2 = __expf(m2 - ms), e3 = __expf(m3 - ms);
    float denom = lt[0][mq] * e0 + lt[1][mq] * e1 + lt[2][mq] * e2 + lt[3][mq] * e3;
    float inv = 1.f / denom;
    float4 o0 = *(float4*)&obuf[0][mq][d4];
    float4 o1 = *(float4*)&obuf[1][mq][d4];
    float4 o2 = *(float4*)&obuf[2][mq][d4];
    float4 o3 = *(float4*)&obuf[3][mq][d4];
    float r0 = (o0.x * e0 + o1.x * e1 + o2.x * e2 + o3.x * e3) * inv;
    float r1 = (o0.y * e0 + o1.y * e1 + o2.y * e2 + o3.y * e3) * inv;
    float r2 = (o0.z * e0 + o1.z * e1 + o2.z * e2 + o3.z * e3) * inv;
    float r3 = (o0.w * e0 + o1.w * e1 + o2.w * e2 + o3.w * e3) * inv;
    uint2 ow;
    ow.x = pack2(r0, r1); ow.y = pack2(r2, r3);
    *reinterpret_cast<uint2*>(attb + (b * NQS + qt * 16 + mq) * DM + h * DK + d4) = ow;
}

// ---------------------------------------------------------------------------
extern "C" void kernel_launch(void* const* d_in, const int* in_sizes, int n_in,
                              void* d_out, int out_size, void* d_ws, size_t ws_size,
                              hipStream_t stream)
{
    const float* query = (const float*)d_in[0];
    const float* key   = (const float*)d_in[1];
    const float* value = (const float*)d_in[2];
    const float* qx    = (const float*)d_in[3];
    const float* qy    = (const float*)d_in[4];
    const float* kx    = (const float*)d_in[5];
    const float* ky    = (const float*)d_in[6];
    const float* Wq    = (const float*)d_in[7];
    const float* bq    = (const float*)d_in[8];
    const float* Wk    = (const float*)d_in[9];
    const float* bk    = (const float*)d_in[10];
    const float* Wv    = (const float*)d_in[11];
    const float* bv    = (const float*)d_in[12];
    const float* Wo    = (const float*)d_in[13];
    const float* bo    = (const float*)d_in[14];
    const float* xt    = (const float*)d_in[15];
    const float* yt    = (const float*)d_in[16];
    const float* Wb    = (const float*)d_in[17];
    const float* bbp   = (const float*)d_in[18];
    float* out = (float*)d_out;

    float* ws = (float*)d_ws;
    float* xproj = ws;                                   // 640064
    float* yproj = xproj + 640064;                       // 640064
    ushort_t* biasf = (ushort_t*)(yproj + 640064);       // 8388608 bf16 = 4194304 f32 slots
    float* p = yproj + 640064 + 4194304;
    ushort_t* qbh  = (ushort_t*)p;                       // (B,H,512,64) bf16
    ushort_t* kbh  = (ushort_t*)(p + 524288);            // (B,H,512,64) bf16
    ushort_t* vtb  = (ushort_t*)(p + 2 * 524288);        // (B,H,64,512) bf16
    ushort_t* attb = (ushort_t*)(p + 3 * 524288);        // (B,512,1024) bf16
    ushort_t* qc   = (ushort_t*)(p + 4 * 524288);
    ushort_t* kcb  = (ushort_t*)(p + 5 * 524288);
    ushort_t* vcb  = (ushort_t*)(p + 6 * 524288);
    ushort_t* wqt  = (ushort_t*)(p + 7 * 524288);
    ushort_t* wkt  = (ushort_t*)(p + 8 * 524288);
    ushort_t* wvt  = (ushort_t*)(p + 9 * 524288);
    ushort_t* wot  = (ushort_t*)(p + 10 * 524288);

    cvt_k<<<dim3(512, 1, 7), dim3(256), 0, stream>>>(
        query, key, value, Wq, Wk, Wv, Wo, qc, kcb, vcb, wqt, wkt, wvt, wot);
    proj_tables_k<<<dim3((2 * NE * HH + 255) / 256), dim3(256), 0, stream>>>(
        xt, yt, Wb, xproj, yproj);
    bias_k<<<dim3(32, 32, 2), dim3(256), 0, stream>>>(
        xproj, yproj, qx, qy, kx, ky, bbp, biasf);
    gemm_bf16_k<1><<<dim3(16, 16, 3), dim3(256), 0, stream>>>(
        qc, kcb, vcb, wqt, wkt, wvt, bq, bk, bv, qbh, kbh, vtb, nullptr);
    attn_k<<<dim3(32, 16, 2), dim3(256), 0, stream>>>(
        qbh, kbh, vtb, biasf, attb);
    gemm_bf16_k<0><<<dim3(16, 16, 1), dim3(256), 0, stream>>>(
        attb, attb, attb, wot, wot, wot, bo, bo, bo, nullptr, nullptr, nullptr, out);
}

// Round 5
// 92.582 us; speedup vs baseline: 2.7050x; 1.0392x over previous
//
#include <hip/hip_runtime.h>
#include <math.h>

#define HH 16
#define DM 1024
#define DK 64
#define NE 40001
#define NB 2
#define NQS 512
#define NKS 512

typedef unsigned short ushort_t;
typedef __attribute__((ext_vector_type(8))) short short8v;
typedef __attribute__((ext_vector_type(4))) float f32x4;

__device__ __forceinline__ ushort_t f2bf(float f) {
    union { float f; unsigned u; } v; v.f = f;
    unsigned r = v.u + 0x7FFFu + ((v.u >> 16) & 1u);
    return (ushort_t)(r >> 16);
}
__device__ __forceinline__ unsigned pack2(float a, float b) {
    return (unsigned)f2bf(a) | ((unsigned)f2bf(b) << 16);
}
__device__ __forceinline__ float asf(unsigned u) {
    union { unsigned u; float f; } v; v.u = u; return v.f;
}

// ---------------------------------------------------------------------------
// Kernel 0: weight transpose-convert (row-major [K][N] fp32 -> [N][K] bf16).
// z in {0,1,2,3} -> Wq, Wk, Wv, Wo.
// ---------------------------------------------------------------------------
__global__ __launch_bounds__(256) void cvt_k(
    const float* __restrict__ wq, const float* __restrict__ wk,
    const float* __restrict__ wv, const float* __restrict__ wo,
    ushort_t* __restrict__ wqt, ushort_t* __restrict__ wkt,
    ushort_t* __restrict__ wvt, ushort_t* __restrict__ wot)
{
    const int z = blockIdx.z;
    const int t = blockIdx.x * 256 + threadIdx.x;   // 0..131071
    const float* w = (z == 0) ? wq : ((z == 1) ? wk : ((z == 2) ? wv : wo));
    ushort_t* wt = (z == 0) ? wqt : ((z == 1) ? wkt : ((z == 2) ? wvt : wot));
    const int n = t & 1023;
    const int k0 = (t >> 10) << 3;
    float e[8];
#pragma unroll
    for (int j = 0; j < 8; ++j) e[j] = w[(k0 + j) * 1024 + n];
    uint4 o;
    o.x = pack2(e[0], e[1]); o.y = pack2(e[2], e[3]);
    o.z = pack2(e[4], e[5]); o.w = pack2(e[6], e[7]);
    *reinterpret_cast<uint4*>(wt + n * 1024 + k0) = o;
}

// ---------------------------------------------------------------------------
// Kernel 1: project embedding tables through Wb (shared across heads):
//   xproj[i][h] = sum_d x_table[i, h*16+d] * Wb[d]  -> stored bf16 (L2-resident)
// ---------------------------------------------------------------------------
__global__ __launch_bounds__(256) void proj_tables_k(
    const float* __restrict__ xt, const float* __restrict__ yt,
    const float* __restrict__ Wb,
    ushort_t* __restrict__ xproj, ushort_t* __restrict__ yproj)
{
    int gid = blockIdx.x * 256 + threadIdx.x;
    const int tot = NE * HH;            // 640016
    if (gid >= 2 * tot) return;
    const float* tab = xt;
    ushort_t* dst = xproj;
    int r = gid;
    if (r >= tot) { r -= tot; tab = yt; dst = yproj; }
    int i = r >> 4, h = r & 15;
    const float4* p = (const float4*)(tab + i * 256 + h * 16);
    float4 w0 = *(const float4*)(Wb);
    float4 w1 = *(const float4*)(Wb + 4);
    float4 w2 = *(const float4*)(Wb + 8);
    float4 w3 = *(const float4*)(Wb + 12);
    float4 p0 = p[0], p1 = p[1], p2 = p[2], p3 = p[3];
    float s = p0.x * w0.x + p0.y * w0.y + p0.z * w0.z + p0.w * w0.w
            + p1.x * w1.x + p1.y * w1.y + p1.z * w1.z + p1.w * w1.w
            + p2.x * w2.x + p2.y * w2.y + p2.z * w2.z + p2.w * w2.w
            + p3.x * w3.x + p3.y * w3.y + p3.z * w3.z + p3.w * w3.w;
    dst[r] = f2bf(s);
}

// ---------------------------------------------------------------------------
// Kernel 2: bias precompute in MFMA-fragment layout (HW-verified in round 3).
// Block = one 16x16 (qt,kt) tile for all 16 heads; gathers the two bf16
// 16-entry projected rows once per (q,k) pair.
// ---------------------------------------------------------------------------
__global__ __launch_bounds__(256) void bias_k(
    const ushort_t* __restrict__ xproj, const ushort_t* __restrict__ yproj,
    const float* __restrict__ qx, const float* __restrict__ qy,
    const float* __restrict__ kx, const float* __restrict__ ky,
    const float* __restrict__ bbp,
    ushort_t* __restrict__ biasf)
{
    const int t = threadIdx.x;
    const int qt = blockIdx.x, kt = blockIdx.y, b = blockIdx.z;
    const int ql = t & 15, kl = t >> 4;
    const int qg = qt * 16 + ql, kg = kt * 16 + kl;

    float dx = qx[b * NKS + kg] - kx[b * NQS + qg];
    float dy = qy[b * NKS + kg] - ky[b * NQS + qg];
    int ix = (int)rintf((fminf(fmaxf(dx, -1000.f), 1000.f) + 1000.f) * 20.f);
    int iy = (int)rintf((fminf(fmaxf(dy, -1000.f), 1000.f) + 1000.f) * 20.f);
    const float bb = bbp[0];

    uint4 xw0 = *(const uint4*)(xproj + ix * 16);
    uint4 xw1 = *(const uint4*)(xproj + ix * 16 + 8);
    uint4 yw0 = *(const uint4*)(yproj + iy * 16);
    uint4 yw1 = *(const uint4*)(yproj + iy * 16 + 8);

    float xa[16], ya[16];
    {
        unsigned u[8] = {xw0.x, xw0.y, xw0.z, xw0.w, xw1.x, xw1.y, xw1.z, xw1.w};
        unsigned v[8] = {yw0.x, yw0.y, yw0.z, yw0.w, yw1.x, yw1.y, yw1.z, yw1.w};
#pragma unroll
        for (int wv = 0; wv < 8; ++wv) {
            xa[2 * wv]     = asf(u[wv] << 16);
            xa[2 * wv + 1] = asf(u[wv] & 0xFFFF0000u);
            ya[2 * wv]     = asf(v[wv] << 16);
            ya[2 * wv + 1] = asf(v[wv] & 0xFFFF0000u);
        }
    }
    const int lane_j = ((kl >> 2) * 16 + ql) * 4 + (kl & 3);
#pragma unroll
    for (int h = 0; h < HH; ++h) {
        float t2 = xa[h] + ya[h] + bb;
        float sig = 1.f / (1.f + __expf(-t2));
        biasf[((b * HH + h) * 32 + kt) * (32 * 256) + qt * 256 + lane_j] = f2bf(sig);
    }
}

// ---------------------------------------------------------------------------
// Kernel 3: bf16 MFMA GEMM, 64x64 tile, BK=64, 4 waves of 32x32.
// EPI=1: A is fp32 (query/key/value), converted to bf16 during LDS staging;
//        z in {0,1,2} -> Q (B,H,N,64) bf16 ; K same layout but pre-scaled by
//        0.125 (exact, power of two) ; V (B,H,64,N) bf16 transposed.
// EPI=0: A is bf16 (attb); plain [M][N] fp32 output (Wo projection).
// B: [N][1024] bf16 (pre-transposed W).
// ---------------------------------------------------------------------------
template<int EPI>
__global__ __launch_bounds__(256) void gemm_bf16_k(
    const void* __restrict__ A0v, const void* __restrict__ A1v, const void* __restrict__ A2v,
    const ushort_t* __restrict__ B0, const ushort_t* __restrict__ B1, const ushort_t* __restrict__ B2,
    const float* __restrict__ bi0, const float* __restrict__ bi1, const float* __restrict__ bi2,
    ushort_t* __restrict__ Yh0, ushort_t* __restrict__ Yh1, ushort_t* __restrict__ Yh2,
    float* __restrict__ Yf)
{
    __shared__ ushort_t As[64][72];
    __shared__ ushort_t Bs[64][72];
    const int z = blockIdx.z;
    const void* Av = (z == 0) ? A0v : ((z == 1) ? A1v : A2v);
    const float* Af = (const float*)Av;
    const ushort_t* Ah = (const ushort_t*)Av;
    const ushort_t* Bp = (z == 0) ? B0 : ((z == 1) ? B1 : B2);
    const float* bi = (z == 0) ? bi0 : ((z == 1) ? bi1 : bi2);
    ushort_t* Yh = (z == 0) ? Yh0 : ((z == 1) ? Yh1 : Yh2);
    const int m0 = blockIdx.y * 64, n0 = blockIdx.x * 64;
    const int tid = threadIdx.x;
    const int lane = tid & 63, w = tid >> 6;
    const int wm = w >> 1, wn = w & 1;
    const int srow = tid >> 2, scg = (tid & 3) * 16;

    f32x4 acc[2][2] = {};
    float4 arf0, arf1, arf2, arf3;
    uint4 arh0, arh1, brh0, brh1;

    auto loadA = [&](int kk) {
        if (EPI) {
            const float* ap = Af + (m0 + srow) * 1024 + kk + scg;
            arf0 = *(const float4*)(ap);
            arf1 = *(const float4*)(ap + 4);
            arf2 = *(const float4*)(ap + 8);
            arf3 = *(const float4*)(ap + 12);
        } else {
            const ushort_t* ap = Ah + (m0 + srow) * 1024 + kk + scg;
            arh0 = *(const uint4*)(ap);
            arh1 = *(const uint4*)(ap + 8);
        }
    };
    auto loadB = [&](int kk) {
        const ushort_t* bp = Bp + (n0 + srow) * 1024 + kk + scg;
        brh0 = *(const uint4*)(bp);
        brh1 = *(const uint4*)(bp + 8);
    };
    loadA(0); loadB(0);

    const int fr = lane & 15;            // frag row/col within 16
    const int ko = (lane >> 4) * 8;      // k offset within 32

    for (int k0 = 0; k0 < 1024; k0 += 64) {
        __syncthreads();
        if (EPI) {
            uint4 w0, w1;
            w0.x = pack2(arf0.x, arf0.y); w0.y = pack2(arf0.z, arf0.w);
            w0.z = pack2(arf1.x, arf1.y); w0.w = pack2(arf1.z, arf1.w);
            w1.x = pack2(arf2.x, arf2.y); w1.y = pack2(arf2.z, arf2.w);
            w1.z = pack2(arf3.x, arf3.y); w1.w = pack2(arf3.z, arf3.w);
            *(uint4*)&As[srow][scg]     = w0;
            *(uint4*)&As[srow][scg + 8] = w1;
        } else {
            *(uint4*)&As[srow][scg]     = arh0;
            *(uint4*)&As[srow][scg + 8] = arh1;
        }
        *(uint4*)&Bs[srow][scg]     = brh0;
        *(uint4*)&Bs[srow][scg + 8] = brh1;
        __syncthreads();
        if (k0 + 64 < 1024) { loadA(k0 + 64); loadB(k0 + 64); }
#pragma unroll
        for (int ks = 0; ks < 64; ks += 32) {
            short8v af0 = *(const short8v*)&As[wm * 32 + fr][ks + ko];
            short8v af1 = *(const short8v*)&As[wm * 32 + 16 + fr][ks + ko];
            short8v bf0 = *(const short8v*)&Bs[wn * 32 + fr][ks + ko];
            short8v bf1 = *(const short8v*)&Bs[wn * 32 + 16 + fr][ks + ko];
            acc[0][0] = __builtin_amdgcn_mfma_f32_16x16x32_bf16(af0, bf0, acc[0][0], 0, 0, 0);
            acc[0][1] = __builtin_amdgcn_mfma_f32_16x16x32_bf16(af0, bf1, acc[0][1], 0, 0, 0);
            acc[1][0] = __builtin_amdgcn_mfma_f32_16x16x32_bf16(af1, bf0, acc[1][0], 0, 0, 0);
            acc[1][1] = __builtin_amdgcn_mfma_f32_16x16x32_bf16(af1, bf1, acc[1][1], 0, 0, 0);
        }
    }

    const int cr = (lane >> 4) * 4;      // C row base (+reg j)
    const int cc = lane & 15;            // C col
#pragma unroll
    for (int m = 0; m < 2; ++m) {
#pragma unroll
        for (int n = 0; n < 2; ++n) {
            int grow = m0 + wm * 32 + m * 16 + cr;
            int gcol = n0 + wn * 32 + n * 16 + cc;
            float bv = bi[gcol];
            if (EPI == 0) {
#pragma unroll
                for (int j = 0; j < 4; ++j)
                    Yf[(grow + j) * 1024 + gcol] = acc[m][n][j] + bv;
            } else {
                int hh = gcol >> 6, dd = gcol & 63;
                if (z == 0) {
#pragma unroll
                    for (int j = 0; j < 4; ++j) {
                        int r = grow + j, bb_ = r >> 9, nn = r & 511;
                        Yh[((bb_ * HH + hh) * NQS + nn) * DK + dd] = f2bf(acc[m][n][j] + bv);
                    }
                } else if (z == 1) {
                    // K pre-scaled by 1/sqrt(DK) = 0.125 (exact power-of-two)
#pragma unroll
                    for (int j = 0; j < 4; ++j) {
                        int r = grow + j, bb_ = r >> 9, nn = r & 511;
                        Yh[((bb_ * HH + hh) * NQS + nn) * DK + dd] = f2bf((acc[m][n][j] + bv) * 0.125f);
                    }
                } else {
                    // V: (B,H,64,N) bf16 transposed
#pragma unroll
                    for (int j = 0; j < 4; ++j) {
                        int r = grow + j, bb_ = r >> 9, nn = r & 511;
                        Yh[((bb_ * HH + hh) * DK + dd) * NKS + nn] = f2bf(acc[m][n][j] + bv);
                    }
                }
            }
        }
    }
}

// ---------------------------------------------------------------------------
// Kernel 4: MFMA flash attention, swapped operands (round-3 verified).
// Score scale already folded into K. Bias read in fragment layout.
// ---------------------------------------------------------------------------
__global__ __launch_bounds__(256, 4) void attn_k(
    const ushort_t* __restrict__ qbh, const ushort_t* __restrict__ kbh,
    const ushort_t* __restrict__ vtb, const ushort_t* __restrict__ biasf,
    ushort_t* __restrict__ attb)
{
    __shared__ ushort_t pst[4][16][40];     // per-wave P tiles [q][k32] (+pad)
    __shared__ float obuf[4][16][76];       // per-wave O^T partials [q][d]
    __shared__ float mt[4][16], lt[4][16];

    const int tid = threadIdx.x;
    const int wid = tid >> 6, lane = tid & 63;
    const int q = lane & 15, g = lane >> 4;
    const int qt = blockIdx.x;
    const int h = blockIdx.y, b = blockIdx.z;
    const int bh = b * HH + h;

    const ushort_t* Qp = qbh + (bh * NQS + qt * 16 + q) * DK + g * 8;
    short8v qf0 = *(const short8v*)Qp;
    short8v qf1 = *(const short8v*)(Qp + 32);

    f32x4 oacc[4] = {};
    float m = -1e30f, l = 0.f;

#pragma unroll 2
    for (int c = 0; c < 4; ++c) {
        const int kc = wid * 128 + c * 32;
        const ushort_t* Kp = kbh + (bh * NKS + kc + q) * DK + g * 8;
        short8v kf00 = *(const short8v*)(Kp);
        short8v kf01 = *(const short8v*)(Kp + 32);
        short8v kf10 = *(const short8v*)(Kp + 16 * DK);
        short8v kf11 = *(const short8v*)(Kp + 16 * DK + 32);

        f32x4 s0 = {0.f, 0.f, 0.f, 0.f};
        f32x4 s1 = {0.f, 0.f, 0.f, 0.f};
        s0 = __builtin_amdgcn_mfma_f32_16x16x32_bf16(kf00, qf0, s0, 0, 0, 0);
        s0 = __builtin_amdgcn_mfma_f32_16x16x32_bf16(kf01, qf1, s0, 0, 0, 0);
        s1 = __builtin_amdgcn_mfma_f32_16x16x32_bf16(kf10, qf0, s1, 0, 0, 0);
        s1 = __builtin_amdgcn_mfma_f32_16x16x32_bf16(kf11, qf1, s1, 0, 0, 0);

        // bias (fragment layout): tiles kt, kt+1
        const int kt = kc >> 4;
        uint2 b0 = *((const uint2*)(biasf + ((bh * 32 + kt) * 32 + qt) * 256) + lane);
        uint2 b1 = *((const uint2*)(biasf + ((bh * 32 + kt + 1) * 32 + qt) * 256) + lane);

        float sv[8];
        sv[0] = s0[0] + asf(b0.x << 16);
        sv[1] = s0[1] + asf(b0.x & 0xFFFF0000u);
        sv[2] = s0[2] + asf(b0.y << 16);
        sv[3] = s0[3] + asf(b0.y & 0xFFFF0000u);
        sv[4] = s1[0] + asf(b1.x << 16);
        sv[5] = s1[1] + asf(b1.x & 0xFFFF0000u);
        sv[6] = s1[2] + asf(b1.y << 16);
        sv[7] = s1[3] + asf(b1.y & 0xFFFF0000u);

        // row max across this lane's 8 + the 3 other g-lanes of column q
        float mc = fmaxf(fmaxf(fmaxf(sv[0], sv[1]), fmaxf(sv[2], sv[3])),
                         fmaxf(fmaxf(sv[4], sv[5]), fmaxf(sv[6], sv[7])));
        mc = fmaxf(mc, __shfl_xor(mc, 16));
        mc = fmaxf(mc, __shfl_xor(mc, 32));
        float mn = fmaxf(m, mc);

        float p[8], ps = 0.f;
#pragma unroll
        for (int j = 0; j < 8; ++j) { p[j] = __expf(sv[j] - mn); ps += p[j]; }
        float sc = __expf(m - mn);
        l = l * sc + ps;
        m = mn;
#pragma unroll
        for (int dt = 0; dt < 4; ++dt)
#pragma unroll
            for (int j = 0; j < 4; ++j) oacc[dt][j] *= sc;

        // P^T fragment via per-wave LDS tile
        ushort_t* prow = &pst[wid][q][0];
        *(unsigned*)(prow + 4 * g)          = pack2(p[0], p[1]);
        *(unsigned*)(prow + 4 * g + 2)      = pack2(p[2], p[3]);
        *(unsigned*)(prow + 16 + 4 * g)     = pack2(p[4], p[5]);
        *(unsigned*)(prow + 16 + 4 * g + 2) = pack2(p[6], p[7]);
        short8v pf = *(const short8v*)&pst[wid][q][8 * g];

        // O^T += V^T . P^T over this chunk's 32 k
        const ushort_t* Vp = vtb + (bh * DK + q) * NKS + kc + g * 8;
#pragma unroll
        for (int dt = 0; dt < 4; ++dt) {
            short8v vf = *(const short8v*)(Vp + dt * 16 * NKS);
            oacc[dt] = __builtin_amdgcn_mfma_f32_16x16x32_bf16(vf, pf, oacc[dt], 0, 0, 0);
        }
    }

    // intra-wave l across the 4 g-lanes of each q (m already shared)
    float lr = l + __shfl_xor(l, 16);
    lr = lr + __shfl_xor(lr, 32);
    if (lane < 16) { mt[wid][lane] = m; lt[wid][lane] = lr; }
#pragma unroll
    for (int dt = 0; dt < 4; ++dt)
#pragma unroll
        for (int j = 0; j < 4; ++j)
            obuf[wid][q][dt * 16 + 4 * g + j] = oacc[dt][j];
    __syncthreads();

    // merge 4 wave-partials: thread -> (q = tid>>4, d4 = (tid&15)*4)
    const int mq = tid >> 4, d4 = (tid & 15) * 4;
    float m0 = mt[0][mq], m1 = mt[1][mq], m2 = mt[2][mq], m3 = mt[3][mq];
    float ms = fmaxf(fmaxf(m0, m1), fmaxf(m2, m3));
    float e0 = __expf(m0 - ms), e1 = __expf(m1 - ms);
    float e2 = __expf(m2 - ms), e3 = __expf(m3 - ms);
    float denom = lt[0][mq] * e0 + lt[1][mq] * e1 + lt[2][mq] * e2 + lt[3][mq] * e3;
    float inv = 1.f / denom;
    float4 o0 = *(float4*)&obuf[0][mq][d4];
    float4 o1 = *(float4*)&obuf[1][mq][d4];
    float4 o2 = *(float4*)&obuf[2][mq][d4];
    float4 o3 = *(float4*)&obuf[3][mq][d4];
    float r0 = (o0.x * e0 + o1.x * e1 + o2.x * e2 + o3.x * e3) * inv;
    float r1 = (o0.y * e0 + o1.y * e1 + o2.y * e2 + o3.y * e3) * inv;
    float r2 = (o0.z * e0 + o1.z * e1 + o2.z * e2 + o3.z * e3) * inv;
    float r3 = (o0.w * e0 + o1.w * e1 + o2.w * e2 + o3.w * e3) * inv;
    uint2 ow;
    ow.x = pack2(r0, r1); ow.y = pack2(r2, r3);
    *reinterpret_cast<uint2*>(attb + (b * NQS + qt * 16 + mq) * DM + h * DK + d4) = ow;
}

// ---------------------------------------------------------------------------
extern "C" void kernel_launch(void* const* d_in, const int* in_sizes, int n_in,
                              void* d_out, int out_size, void* d_ws, size_t ws_size,
                              hipStream_t stream)
{
    const float* query = (const float*)d_in[0];
    const float* key   = (const float*)d_in[1];
    const float* value = (const float*)d_in[2];
    const float* qx    = (const float*)d_in[3];
    const float* qy    = (const float*)d_in[4];
    const float* kx    = (const float*)d_in[5];
    const float* ky    = (const float*)d_in[6];
    const float* Wq    = (const float*)d_in[7];
    const float* bq    = (const float*)d_in[8];
    const float* Wk    = (const float*)d_in[9];
    const float* bk    = (const float*)d_in[10];
    const float* Wv    = (const float*)d_in[11];
    const float* bv    = (const float*)d_in[12];
    const float* Wo    = (const float*)d_in[13];
    const float* bo    = (const float*)d_in[14];
    const float* xt    = (const float*)d_in[15];
    const float* yt    = (const float*)d_in[16];
    const float* Wb    = (const float*)d_in[17];
    const float* bbp   = (const float*)d_in[18];
    float* out = (float*)d_out;

    // ws layout — ALL offsets in ushort (bf16) units.
    // (B,H,512,64) buffers are 2*16*512*64 = 1,048,576 elements each.
    ushort_t* xprojh = (ushort_t*)d_ws;                  //   640,064
    ushort_t* yprojh = xprojh + 640064;                  //   640,064
    ushort_t* biasf  = yprojh + 640064;                  // 8,388,608  (B,H,32,32,256)
    ushort_t* qbh    = biasf + 8388608;                  // 1,048,576  (B,H,512,64)
    ushort_t* kbh    = qbh + 1048576;                    // 1,048,576
    ushort_t* vtb    = kbh + 1048576;                    // 1,048,576  (B,H,64,512)
    ushort_t* attb   = vtb + 1048576;                    // 1,048,576  (B,512,1024)
    ushort_t* wqt    = attb + 1048576;                   // 1,048,576 each
    ushort_t* wkt    = wqt + 1048576;
    ushort_t* wvt    = wkt + 1048576;
    ushort_t* wot    = wvt + 1048576;

    cvt_k<<<dim3(512, 1, 4), dim3(256), 0, stream>>>(
        Wq, Wk, Wv, Wo, wqt, wkt, wvt, wot);
    proj_tables_k<<<dim3((2 * NE * HH + 255) / 256), dim3(256), 0, stream>>>(
        xt, yt, Wb, xprojh, yprojh);
    bias_k<<<dim3(32, 32, 2), dim3(256), 0, stream>>>(
        xprojh, yprojh, qx, qy, kx, ky, bbp, biasf);
    gemm_bf16_k<1><<<dim3(16, 16, 3), dim3(256), 0, stream>>>(
        query, key, value, wqt, wkt, wvt, bq, bk, bv, qbh, kbh, vtb, nullptr);
    attn_k<<<dim3(32, 16, 2), dim3(256), 0, stream>>>(
        qbh, kbh, vtb, biasf, attb);
    gemm_bf16_k<0><<<dim3(16, 16, 1), dim3(256), 0, stream>>>(
        attb, attb, attb, wot, wot, wot, bo, bo, bo, nullptr, nullptr, nullptr, out);
}

// Round 6
// 84.155 us; speedup vs baseline: 2.9759x; 1.1001x over previous
//
#include <hip/hip_runtime.h>
#include <math.h>

#define HH 16
#define DM 1024
#define DK 64
#define NE 40001
#define NB 2
#define NQS 512
#define NKS 512

typedef unsigned short ushort_t;
typedef __attribute__((ext_vector_type(8))) short short8v;
typedef __attribute__((ext_vector_type(4))) float f32x4;

__device__ __forceinline__ ushort_t f2bf(float f) {
    union { float f; unsigned u; } v; v.f = f;
    unsigned r = v.u + 0x7FFFu + ((v.u >> 16) & 1u);
    return (ushort_t)(r >> 16);
}
__device__ __forceinline__ unsigned pack2(float a, float b) {
    return (unsigned)f2bf(a) | ((unsigned)f2bf(b) << 16);
}
__device__ __forceinline__ float asf(unsigned u) {
    union { unsigned u; float f; } v; v.u = u; return v.f;
}

// ---------------------------------------------------------------------------
// Kernel A (prep): fused table-projection + weight transpose-convert.
//   blocks [0, 5001)           : proj  — xproj[i][h] = sum_d xt[i,h*16+d]*Wb[d]
//   blocks [5001, 5001+2048)   : cvt   — W [K][N] fp32 -> [N][K] bf16, z=W sel
// Both memory-bound; one launch ≈ HBM floor for ~110 MB.
// ---------------------------------------------------------------------------
__global__ __launch_bounds__(256) void prep_k(
    const float* __restrict__ xt, const float* __restrict__ yt,
    const float* __restrict__ Wb,
    const float* __restrict__ wq, const float* __restrict__ wk,
    const float* __restrict__ wv, const float* __restrict__ wo,
    ushort_t* __restrict__ xproj, ushort_t* __restrict__ yproj,
    ushort_t* __restrict__ wqt, ushort_t* __restrict__ wkt,
    ushort_t* __restrict__ wvt, ushort_t* __restrict__ wot)
{
    const int bid = blockIdx.x;
    if (bid < 5001) {
        int gid = bid * 256 + threadIdx.x;
        const int tot = NE * HH;            // 640016
        if (gid >= 2 * tot) return;
        const float* tab = xt;
        ushort_t* dst = xproj;
        int r = gid;
        if (r >= tot) { r -= tot; tab = yt; dst = yproj; }
        int i = r >> 4, h = r & 15;
        const float4* p = (const float4*)(tab + i * 256 + h * 16);
        float4 w0 = *(const float4*)(Wb);
        float4 w1 = *(const float4*)(Wb + 4);
        float4 w2 = *(const float4*)(Wb + 8);
        float4 w3 = *(const float4*)(Wb + 12);
        float4 p0 = p[0], p1 = p[1], p2 = p[2], p3 = p[3];
        float s = p0.x * w0.x + p0.y * w0.y + p0.z * w0.z + p0.w * w0.w
                + p1.x * w1.x + p1.y * w1.y + p1.z * w1.z + p1.w * w1.w
                + p2.x * w2.x + p2.y * w2.y + p2.z * w2.z + p2.w * w2.w
                + p3.x * w3.x + p3.y * w3.y + p3.z * w3.z + p3.w * w3.w;
        dst[r] = f2bf(s);
    } else {
        const int c = bid - 5001;              // 0..2047
        const int z = c >> 9;                  // weight select
        const int t = (c & 511) * 256 + threadIdx.x;   // 0..131071
        const float* w = (z == 0) ? wq : ((z == 1) ? wk : ((z == 2) ? wv : wo));
        ushort_t* wt = (z == 0) ? wqt : ((z == 1) ? wkt : ((z == 2) ? wvt : wot));
        const int n = t & 1023;
        const int k0 = (t >> 10) << 3;
        float e[8];
#pragma unroll
        for (int j = 0; j < 8; ++j) e[j] = w[(k0 + j) * 1024 + n];
        uint4 o;
        o.x = pack2(e[0], e[1]); o.y = pack2(e[2], e[3]);
        o.z = pack2(e[4], e[5]); o.w = pack2(e[6], e[7]);
        *reinterpret_cast<uint4*>(wt + n * 1024 + k0) = o;
    }
}

// ---------------------------------------------------------------------------
// Kernel B (biasqkv): fused QKV MFMA GEMM + bias precompute.
//   blocks [0, 768)       : GEMM — z=bid>>8 in {Q,K,V}, y=(bid>>4)&15, x=bid&15
//                           (dispatched first so MFMA blocks start immediately)
//   blocks [768, 768+2048): bias in MFMA-fragment layout (round-3 verified)
// GEMM: 64x64 tile, BK=64, A fp32 converted during LDS staging.
//   Q -> (B,H,N,64) bf16 ; K same, pre-scaled 0.125 ; V -> (B,H,64,N) bf16.
// ---------------------------------------------------------------------------
__global__ __launch_bounds__(256) void biasqkv_k(
    const float* __restrict__ A0f, const float* __restrict__ A1f, const float* __restrict__ A2f,
    const ushort_t* __restrict__ B0, const ushort_t* __restrict__ B1, const ushort_t* __restrict__ B2,
    const float* __restrict__ bi0, const float* __restrict__ bi1, const float* __restrict__ bi2,
    ushort_t* __restrict__ Yh0, ushort_t* __restrict__ Yh1, ushort_t* __restrict__ Yh2,
    const ushort_t* __restrict__ xproj, const ushort_t* __restrict__ yproj,
    const float* __restrict__ qx, const float* __restrict__ qy,
    const float* __restrict__ kx, const float* __restrict__ ky,
    const float* __restrict__ bbp,
    ushort_t* __restrict__ biasf)
{
    __shared__ ushort_t As[64][72];
    __shared__ ushort_t Bs[64][72];
    const int bid = blockIdx.x;
    const int tid = threadIdx.x;

    if (bid < 768) {
        // ---------------- GEMM path ----------------
        const int z = bid >> 8, by = (bid >> 4) & 15, bx = bid & 15;
        const float* Af = (z == 0) ? A0f : ((z == 1) ? A1f : A2f);
        const ushort_t* Bp = (z == 0) ? B0 : ((z == 1) ? B1 : B2);
        const float* bi = (z == 0) ? bi0 : ((z == 1) ? bi1 : bi2);
        ushort_t* Yh = (z == 0) ? Yh0 : ((z == 1) ? Yh1 : Yh2);
        const int m0 = by * 64, n0 = bx * 64;
        const int lane = tid & 63, w = tid >> 6;
        const int wm = w >> 1, wn = w & 1;
        const int srow = tid >> 2, scg = (tid & 3) * 16;

        f32x4 acc[2][2] = {};
        float4 arf0, arf1, arf2, arf3;
        uint4 brh0, brh1;

        auto loadA = [&](int kk) {
            const float* ap = Af + (m0 + srow) * 1024 + kk + scg;
            arf0 = *(const float4*)(ap);
            arf1 = *(const float4*)(ap + 4);
            arf2 = *(const float4*)(ap + 8);
            arf3 = *(const float4*)(ap + 12);
        };
        auto loadB = [&](int kk) {
            const ushort_t* bp = Bp + (n0 + srow) * 1024 + kk + scg;
            brh0 = *(const uint4*)(bp);
            brh1 = *(const uint4*)(bp + 8);
        };
        loadA(0); loadB(0);

        const int fr = lane & 15;            // frag row/col within 16
        const int ko = (lane >> 4) * 8;      // k offset within 32

        for (int k0 = 0; k0 < 1024; k0 += 64) {
            __syncthreads();
            uint4 w0, w1;
            w0.x = pack2(arf0.x, arf0.y); w0.y = pack2(arf0.z, arf0.w);
            w0.z = pack2(arf1.x, arf1.y); w0.w = pack2(arf1.z, arf1.w);
            w1.x = pack2(arf2.x, arf2.y); w1.y = pack2(arf2.z, arf2.w);
            w1.z = pack2(arf3.x, arf3.y); w1.w = pack2(arf3.z, arf3.w);
            *(uint4*)&As[srow][scg]     = w0;
            *(uint4*)&As[srow][scg + 8] = w1;
            *(uint4*)&Bs[srow][scg]     = brh0;
            *(uint4*)&Bs[srow][scg + 8] = brh1;
            __syncthreads();
            if (k0 + 64 < 1024) { loadA(k0 + 64); loadB(k0 + 64); }
#pragma unroll
            for (int ks = 0; ks < 64; ks += 32) {
                short8v af0 = *(const short8v*)&As[wm * 32 + fr][ks + ko];
                short8v af1 = *(const short8v*)&As[wm * 32 + 16 + fr][ks + ko];
                short8v bf0 = *(const short8v*)&Bs[wn * 32 + fr][ks + ko];
                short8v bf1 = *(const short8v*)&Bs[wn * 32 + 16 + fr][ks + ko];
                acc[0][0] = __builtin_amdgcn_mfma_f32_16x16x32_bf16(af0, bf0, acc[0][0], 0, 0, 0);
                acc[0][1] = __builtin_amdgcn_mfma_f32_16x16x32_bf16(af0, bf1, acc[0][1], 0, 0, 0);
                acc[1][0] = __builtin_amdgcn_mfma_f32_16x16x32_bf16(af1, bf0, acc[1][0], 0, 0, 0);
                acc[1][1] = __builtin_amdgcn_mfma_f32_16x16x32_bf16(af1, bf1, acc[1][1], 0, 0, 0);
            }
        }

        const int cr = (lane >> 4) * 4;
        const int cc = lane & 15;
#pragma unroll
        for (int m = 0; m < 2; ++m) {
#pragma unroll
            for (int n = 0; n < 2; ++n) {
                int grow = m0 + wm * 32 + m * 16 + cr;
                int gcol = n0 + wn * 32 + n * 16 + cc;
                float bv = bi[gcol];
                int hh = gcol >> 6, dd = gcol & 63;
                if (z == 0) {
#pragma unroll
                    for (int j = 0; j < 4; ++j) {
                        int r = grow + j, bb_ = r >> 9, nn = r & 511;
                        Yh[((bb_ * HH + hh) * NQS + nn) * DK + dd] = f2bf(acc[m][n][j] + bv);
                    }
                } else if (z == 1) {
                    // K pre-scaled by 1/sqrt(DK) = 0.125 (exact power-of-two)
#pragma unroll
                    for (int j = 0; j < 4; ++j) {
                        int r = grow + j, bb_ = r >> 9, nn = r & 511;
                        Yh[((bb_ * HH + hh) * NQS + nn) * DK + dd] = f2bf((acc[m][n][j] + bv) * 0.125f);
                    }
                } else {
                    // V: (B,H,64,N) bf16 transposed
#pragma unroll
                    for (int j = 0; j < 4; ++j) {
                        int r = grow + j, bb_ = r >> 9, nn = r & 511;
                        Yh[((bb_ * HH + hh) * DK + dd) * NKS + nn] = f2bf(acc[m][n][j] + bv);
                    }
                }
            }
        }
    } else {
        // ---------------- bias path ----------------
        const int r = bid - 768;               // 0..2047
        const int b = r >> 10;
        const int kt = (r >> 5) & 31, qt = r & 31;
        const int ql = tid & 15, kl = tid >> 4;
        const int qg = qt * 16 + ql, kg = kt * 16 + kl;

        float dx = qx[b * NKS + kg] - kx[b * NQS + qg];
        float dy = qy[b * NKS + kg] - ky[b * NQS + qg];
        int ix = (int)rintf((fminf(fmaxf(dx, -1000.f), 1000.f) + 1000.f) * 20.f);
        int iy = (int)rintf((fminf(fmaxf(dy, -1000.f), 1000.f) + 1000.f) * 20.f);
        const float bb = bbp[0];

        uint4 xw0 = *(const uint4*)(xproj + ix * 16);
        uint4 xw1 = *(const uint4*)(xproj + ix * 16 + 8);
        uint4 yw0 = *(const uint4*)(yproj + iy * 16);
        uint4 yw1 = *(const uint4*)(yproj + iy * 16 + 8);

        float xa[16], ya[16];
        {
            unsigned u[8] = {xw0.x, xw0.y, xw0.z, xw0.w, xw1.x, xw1.y, xw1.z, xw1.w};
            unsigned v[8] = {yw0.x, yw0.y, yw0.z, yw0.w, yw1.x, yw1.y, yw1.z, yw1.w};
#pragma unroll
            for (int wv = 0; wv < 8; ++wv) {
                xa[2 * wv]     = asf(u[wv] << 16);
                xa[2 * wv + 1] = asf(u[wv] & 0xFFFF0000u);
                ya[2 * wv]     = asf(v[wv] << 16);
                ya[2 * wv + 1] = asf(v[wv] & 0xFFFF0000u);
            }
        }
        const int lane_j = ((kl >> 2) * 16 + ql) * 4 + (kl & 3);
#pragma unroll
        for (int h = 0; h < HH; ++h) {
            float t2 = xa[h] + ya[h] + bb;
            float sig = 1.f / (1.f + __expf(-t2));
            biasf[((b * HH + h) * 32 + kt) * (32 * 256) + qt * 256 + lane_j] = f2bf(sig);
        }
    }
}

// ---------------------------------------------------------------------------
// Kernel C: MFMA flash attention, swapped operands (round-3 verified).
// Score scale already folded into K. Bias read in fragment layout.
// ---------------------------------------------------------------------------
__global__ __launch_bounds__(256, 4) void attn_k(
    const ushort_t* __restrict__ qbh, const ushort_t* __restrict__ kbh,
    const ushort_t* __restrict__ vtb, const ushort_t* __restrict__ biasf,
    ushort_t* __restrict__ attb)
{
    __shared__ ushort_t pst[4][16][40];     // per-wave P tiles [q][k32] (+pad)
    __shared__ float obuf[4][16][76];       // per-wave O^T partials [q][d]
    __shared__ float mt[4][16], lt[4][16];

    const int tid = threadIdx.x;
    const int wid = tid >> 6, lane = tid & 63;
    const int q = lane & 15, g = lane >> 4;
    const int qt = blockIdx.x;
    const int h = blockIdx.y, b = blockIdx.z;
    const int bh = b * HH + h;

    const ushort_t* Qp = qbh + (bh * NQS + qt * 16 + q) * DK + g * 8;
    short8v qf0 = *(const short8v*)Qp;
    short8v qf1 = *(const short8v*)(Qp + 32);

    f32x4 oacc[4] = {};
    float m = -1e30f, l = 0.f;

#pragma unroll 2
    for (int c = 0; c < 4; ++c) {
        const int kc = wid * 128 + c * 32;
        const ushort_t* Kp = kbh + (bh * NKS + kc + q) * DK + g * 8;
        short8v kf00 = *(const short8v*)(Kp);
        short8v kf01 = *(const short8v*)(Kp + 32);
        short8v kf10 = *(const short8v*)(Kp + 16 * DK);
        short8v kf11 = *(const short8v*)(Kp + 16 * DK + 32);

        f32x4 s0 = {0.f, 0.f, 0.f, 0.f};
        f32x4 s1 = {0.f, 0.f, 0.f, 0.f};
        s0 = __builtin_amdgcn_mfma_f32_16x16x32_bf16(kf00, qf0, s0, 0, 0, 0);
        s0 = __builtin_amdgcn_mfma_f32_16x16x32_bf16(kf01, qf1, s0, 0, 0, 0);
        s1 = __builtin_amdgcn_mfma_f32_16x16x32_bf16(kf10, qf0, s1, 0, 0, 0);
        s1 = __builtin_amdgcn_mfma_f32_16x16x32_bf16(kf11, qf1, s1, 0, 0, 0);

        // bias (fragment layout): tiles kt, kt+1
        const int kt = kc >> 4;
        uint2 b0 = *((const uint2*)(biasf + ((bh * 32 + kt) * 32 + qt) * 256) + lane);
        uint2 b1 = *((const uint2*)(biasf + ((bh * 32 + kt + 1) * 32 + qt) * 256) + lane);

        float sv[8];
        sv[0] = s0[0] + asf(b0.x << 16);
        sv[1] = s0[1] + asf(b0.x & 0xFFFF0000u);
        sv[2] = s0[2] + asf(b0.y << 16);
        sv[3] = s0[3] + asf(b0.y & 0xFFFF0000u);
        sv[4] = s1[0] + asf(b1.x << 16);
        sv[5] = s1[1] + asf(b1.x & 0xFFFF0000u);
        sv[6] = s1[2] + asf(b1.y << 16);
        sv[7] = s1[3] + asf(b1.y & 0xFFFF0000u);

        // row max across this lane's 8 + the 3 other g-lanes of column q
        float mc = fmaxf(fmaxf(fmaxf(sv[0], sv[1]), fmaxf(sv[2], sv[3])),
                         fmaxf(fmaxf(sv[4], sv[5]), fmaxf(sv[6], sv[7])));
        mc = fmaxf(mc, __shfl_xor(mc, 16));
        mc = fmaxf(mc, __shfl_xor(mc, 32));
        float mn = fmaxf(m, mc);

        float p[8], ps = 0.f;
#pragma unroll
        for (int j = 0; j < 8; ++j) { p[j] = __expf(sv[j] - mn); ps += p[j]; }
        float sc = __expf(m - mn);
        l = l * sc + ps;
        m = mn;
#pragma unroll
        for (int dt = 0; dt < 4; ++dt)
#pragma unroll
            for (int j = 0; j < 4; ++j) oacc[dt][j] *= sc;

        // P^T fragment via per-wave LDS tile
        ushort_t* prow = &pst[wid][q][0];
        *(unsigned*)(prow + 4 * g)          = pack2(p[0], p[1]);
        *(unsigned*)(prow + 4 * g + 2)      = pack2(p[2], p[3]);
        *(unsigned*)(prow + 16 + 4 * g)     = pack2(p[4], p[5]);
        *(unsigned*)(prow + 16 + 4 * g + 2) = pack2(p[6], p[7]);
        short8v pf = *(const short8v*)&pst[wid][q][8 * g];

        // O^T += V^T . P^T over this chunk's 32 k
        const ushort_t* Vp = vtb + (bh * DK + q) * NKS + kc + g * 8;
#pragma unroll
        for (int dt = 0; dt < 4; ++dt) {
            short8v vf = *(const short8v*)(Vp + dt * 16 * NKS);
            oacc[dt] = __builtin_amdgcn_mfma_f32_16x16x32_bf16(vf, pf, oacc[dt], 0, 0, 0);
        }
    }

    // intra-wave l across the 4 g-lanes of each q (m already shared)
    float lr = l + __shfl_xor(l, 16);
    lr = lr + __shfl_xor(lr, 32);
    if (lane < 16) { mt[wid][lane] = m; lt[wid][lane] = lr; }
#pragma unroll
    for (int dt = 0; dt < 4; ++dt)
#pragma unroll
        for (int j = 0; j < 4; ++j)
            obuf[wid][q][dt * 16 + 4 * g + j] = oacc[dt][j];
    __syncthreads();

    // merge 4 wave-partials: thread -> (q = tid>>4, d4 = (tid&15)*4)
    const int mq = tid >> 4, d4 = (tid & 15) * 4;
    float m0 = mt[0][mq], m1 = mt[1][mq], m2 = mt[2][mq], m3 = mt[3][mq];
    float ms = fmaxf(fmaxf(m0, m1), fmaxf(m2, m3));
    float e0 = __expf(m0 - ms), e1 = __expf(m1 - ms);
    float e2 = __expf(m2 - ms), e3 = __expf(m3 - ms);
    float denom = lt[0][mq] * e0 + lt[1][mq] * e1 + lt[2][mq] * e2 + lt[3][mq] * e3;
    float inv = 1.f / denom;
    float4 o0 = *(float4*)&obuf[0][mq][d4];
    float4 o1 = *(float4*)&obuf[1][mq][d4];
    float4 o2 = *(float4*)&obuf[2][mq][d4];
    float4 o3 = *(float4*)&obuf[3][mq][d4];
    float r0 = (o0.x * e0 + o1.x * e1 + o2.x * e2 + o3.x * e3) * inv;
    float r1 = (o0.y * e0 + o1.y * e1 + o2.y * e2 + o3.y * e3) * inv;
    float r2 = (o0.z * e0 + o1.z * e1 + o2.z * e2 + o3.z * e3) * inv;
    float r3 = (o0.w * e0 + o1.w * e1 + o2.w * e2 + o3.w * e3) * inv;
    uint2 ow;
    ow.x = pack2(r0, r1); ow.y = pack2(r2, r3);
    *reinterpret_cast<uint2*>(attb + (b * NQS + qt * 16 + mq) * DM + h * DK + d4) = ow;
}

// ---------------------------------------------------------------------------
// Kernel D: output projection GEMM (A bf16 attb, B pre-transposed Wo bf16,
// plain fp32 [M][N] output). 64x64 tile, BK=64, 4 waves of 32x32.
// ---------------------------------------------------------------------------
__global__ __launch_bounds__(256) void ogemm_k(
    const ushort_t* __restrict__ Ah, const ushort_t* __restrict__ Bp,
    const float* __restrict__ bi, float* __restrict__ Yf)
{
    __shared__ ushort_t As[64][72];
    __shared__ ushort_t Bs[64][72];
    const int m0 = blockIdx.y * 64, n0 = blockIdx.x * 64;
    const int tid = threadIdx.x;
    const int lane = tid & 63, w = tid >> 6;
    const int wm = w >> 1, wn = w & 1;
    const int srow = tid >> 2, scg = (tid & 3) * 16;

    f32x4 acc[2][2] = {};
    uint4 arh0, arh1, brh0, brh1;

    auto loadA = [&](int kk) {
        const ushort_t* ap = Ah + (m0 + srow) * 1024 + kk + scg;
        arh0 = *(const uint4*)(ap);
        arh1 = *(const uint4*)(ap + 8);
    };
    auto loadB = [&](int kk) {
        const ushort_t* bp = Bp + (n0 + srow) * 1024 + kk + scg;
        brh0 = *(const uint4*)(bp);
        brh1 = *(const uint4*)(bp + 8);
    };
    loadA(0); loadB(0);

    const int fr = lane & 15;
    const int ko = (lane >> 4) * 8;

    for (int k0 = 0; k0 < 1024; k0 += 64) {
        __syncthreads();
        *(uint4*)&As[srow][scg]     = arh0;
        *(uint4*)&As[srow][scg + 8] = arh1;
        *(uint4*)&Bs[srow][scg]     = brh0;
        *(uint4*)&Bs[srow][scg + 8] = brh1;
        __syncthreads();
        if (k0 + 64 < 1024) { loadA(k0 + 64); loadB(k0 + 64); }
#pragma unroll
        for (int ks = 0; ks < 64; ks += 32) {
            short8v af0 = *(const short8v*)&As[wm * 32 + fr][ks + ko];
            short8v af1 = *(const short8v*)&As[wm * 32 + 16 + fr][ks + ko];
            short8v bf0 = *(const short8v*)&Bs[wn * 32 + fr][ks + ko];
            short8v bf1 = *(const short8v*)&Bs[wn * 32 + 16 + fr][ks + ko];
            acc[0][0] = __builtin_amdgcn_mfma_f32_16x16x32_bf16(af0, bf0, acc[0][0], 0, 0, 0);
            acc[0][1] = __builtin_amdgcn_mfma_f32_16x16x32_bf16(af0, bf1, acc[0][1], 0, 0, 0);
            acc[1][0] = __builtin_amdgcn_mfma_f32_16x16x32_bf16(af1, bf0, acc[1][0], 0, 0, 0);
            acc[1][1] = __builtin_amdgcn_mfma_f32_16x16x32_bf16(af1, bf1, acc[1][1], 0, 0, 0);
        }
    }

    const int cr = (lane >> 4) * 4;
    const int cc = lane & 15;
#pragma unroll
    for (int m = 0; m < 2; ++m) {
#pragma unroll
        for (int n = 0; n < 2; ++n) {
            int grow = m0 + wm * 32 + m * 16 + cr;
            int gcol = n0 + wn * 32 + n * 16 + cc;
            float bv = bi[gcol];
#pragma unroll
            for (int j = 0; j < 4; ++j)
                Yf[(grow + j) * 1024 + gcol] = acc[m][n][j] + bv;
        }
    }
}

// ---------------------------------------------------------------------------
extern "C" void kernel_launch(void* const* d_in, const int* in_sizes, int n_in,
                              void* d_out, int out_size, void* d_ws, size_t ws_size,
                              hipStream_t stream)
{
    const float* query = (const float*)d_in[0];
    const float* key   = (const float*)d_in[1];
    const float* value = (const float*)d_in[2];
    const float* qx    = (const float*)d_in[3];
    const float* qy    = (const float*)d_in[4];
    const float* kx    = (const float*)d_in[5];
    const float* ky    = (const float*)d_in[6];
    const float* Wq    = (const float*)d_in[7];
    const float* bq    = (const float*)d_in[8];
    const float* Wk    = (const float*)d_in[9];
    const float* bk    = (const float*)d_in[10];
    const float* Wv    = (const float*)d_in[11];
    const float* bv    = (const float*)d_in[12];
    const float* Wo    = (const float*)d_in[13];
    const float* bo    = (const float*)d_in[14];
    const float* xt    = (const float*)d_in[15];
    const float* yt    = (const float*)d_in[16];
    const float* Wb    = (const float*)d_in[17];
    const float* bbp   = (const float*)d_in[18];
    float* out = (float*)d_out;

    // ws layout — ALL offsets in ushort (bf16) units.
    ushort_t* xprojh = (ushort_t*)d_ws;                  //   640,064
    ushort_t* yprojh = xprojh + 640064;                  //   640,064
    ushort_t* biasf  = yprojh + 640064;                  // 8,388,608  (B,H,32,32,256)
    ushort_t* qbh    = biasf + 8388608;                  // 1,048,576  (B,H,512,64)
    ushort_t* kbh    = qbh + 1048576;                    // 1,048,576
    ushort_t* vtb    = kbh + 1048576;                    // 1,048,576  (B,H,64,512)
    ushort_t* attb   = vtb + 1048576;                    // 1,048,576  (B,512,1024)
    ushort_t* wqt    = attb + 1048576;                   // 1,048,576 each
    ushort_t* wkt    = wqt + 1048576;
    ushort_t* wvt    = wkt + 1048576;
    ushort_t* wot    = wvt + 1048576;

    prep_k<<<dim3(5001 + 2048), dim3(256), 0, stream>>>(
        xt, yt, Wb, Wq, Wk, Wv, Wo, xprojh, yprojh, wqt, wkt, wvt, wot);
    biasqkv_k<<<dim3(768 + 2048), dim3(256), 0, stream>>>(
        query, key, value, wqt, wkt, wvt, bq, bk, bv, qbh, kbh, vtb,
        xprojh, yprojh, qx, qy, kx, ky, bbp, biasf);
    attn_k<<<dim3(32, 16, 2), dim3(256), 0, stream>>>(
        qbh, kbh, vtb, biasf, attb);
    ogemm_k<<<dim3(16, 16), dim3(256), 0, stream>>>(
        attb, wot, bo, out);
}

// Round 7
// 80.193 us; speedup vs baseline: 3.1229x; 1.0494x over previous
//
#include <hip/hip_runtime.h>
#include <math.h>

#define HH 16
#define DM 1024
#define DK 64
#define NE 40001
#define NB 2
#define NQS 512
#define NKS 512

typedef unsigned short ushort_t;
typedef __attribute__((ext_vector_type(8))) short short8v;
typedef __attribute__((ext_vector_type(4))) float f32x4;

__device__ __forceinline__ ushort_t f2bf(float f) {
    union { float f; unsigned u; } v; v.f = f;
    unsigned r = v.u + 0x7FFFu + ((v.u >> 16) & 1u);
    return (ushort_t)(r >> 16);
}
__device__ __forceinline__ unsigned pack2(float a, float b) {
    return (unsigned)f2bf(a) | ((unsigned)f2bf(b) << 16);
}
__device__ __forceinline__ float asf(unsigned u) {
    union { unsigned u; float f; } v; v.u = u; return v.f;
}

// ---------------------------------------------------------------------------
// Kernel A (prep): fused table-projection + weight transpose-convert + QKV
// copy-convert. All memory-bound; one launch ≈ HBM floor (~123 MB).
//   blocks [0, 5001)        : proj — xproj[i][h] = sum_d xt[i,h*16+d]*Wb[d]
//   blocks [5001, 7049)     : W [K][N] fp32 -> [N][K] bf16 (4 weights)
//   blocks [7049, 8585)     : query/key/value fp32 -> bf16 copy-convert
// ---------------------------------------------------------------------------
__global__ __launch_bounds__(256) void prep_k(
    const float* __restrict__ xt, const float* __restrict__ yt,
    const float* __restrict__ Wb,
    const float* __restrict__ wq, const float* __restrict__ wk,
    const float* __restrict__ wv, const float* __restrict__ wo,
    const float* __restrict__ xq, const float* __restrict__ xk, const float* __restrict__ xv,
    ushort_t* __restrict__ xproj, ushort_t* __restrict__ yproj,
    ushort_t* __restrict__ wqt, ushort_t* __restrict__ wkt,
    ushort_t* __restrict__ wvt, ushort_t* __restrict__ wot,
    ushort_t* __restrict__ qc, ushort_t* __restrict__ kc, ushort_t* __restrict__ vc)
{
    const int bid = blockIdx.x;
    if (bid < 5001) {
        int gid = bid * 256 + threadIdx.x;
        const int tot = NE * HH;            // 640016
        if (gid >= 2 * tot) return;
        const float* tab = xt;
        ushort_t* dst = xproj;
        int r = gid;
        if (r >= tot) { r -= tot; tab = yt; dst = yproj; }
        int i = r >> 4, h = r & 15;
        const float4* p = (const float4*)(tab + i * 256 + h * 16);
        float4 w0 = *(const float4*)(Wb);
        float4 w1 = *(const float4*)(Wb + 4);
        float4 w2 = *(const float4*)(Wb + 8);
        float4 w3 = *(const float4*)(Wb + 12);
        float4 p0 = p[0], p1 = p[1], p2 = p[2], p3 = p[3];
        float s = p0.x * w0.x + p0.y * w0.y + p0.z * w0.z + p0.w * w0.w
                + p1.x * w1.x + p1.y * w1.y + p1.z * w1.z + p1.w * w1.w
                + p2.x * w2.x + p2.y * w2.y + p2.z * w2.z + p2.w * w2.w
                + p3.x * w3.x + p3.y * w3.y + p3.z * w3.z + p3.w * w3.w;
        dst[r] = f2bf(s);
    } else if (bid < 7049) {
        const int c = bid - 5001;              // 0..2047
        const int z = c >> 9;                  // weight select
        const int t = (c & 511) * 256 + threadIdx.x;   // 0..131071
        const float* w = (z == 0) ? wq : ((z == 1) ? wk : ((z == 2) ? wv : wo));
        ushort_t* wt = (z == 0) ? wqt : ((z == 1) ? wkt : ((z == 2) ? wvt : wot));
        const int n = t & 1023;
        const int k0 = (t >> 10) << 3;
        float e[8];
#pragma unroll
        for (int j = 0; j < 8; ++j) e[j] = w[(k0 + j) * 1024 + n];
        uint4 o;
        o.x = pack2(e[0], e[1]); o.y = pack2(e[2], e[3]);
        o.z = pack2(e[4], e[5]); o.w = pack2(e[6], e[7]);
        *reinterpret_cast<uint4*>(wt + n * 1024 + k0) = o;
    } else {
        const int c = bid - 7049;              // 0..1535
        const int z = c >> 9;                  // 0,1,2 -> q,k,v
        const int t = (c & 511) * 256 + threadIdx.x;   // 0..131071
        const float* src = (z == 0) ? xq : ((z == 1) ? xk : xv);
        ushort_t* dst = (z == 0) ? qc : ((z == 1) ? kc : vc);
        float4 a = ((const float4*)src)[t * 2];
        float4 b = ((const float4*)src)[t * 2 + 1];
        uint4 o;
        o.x = pack2(a.x, a.y); o.y = pack2(a.z, a.w);
        o.z = pack2(b.x, b.y); o.w = pack2(b.z, b.w);
        *reinterpret_cast<uint4*>(dst + t * 8) = o;
    }
}

// ---------------------------------------------------------------------------
// Kernel B (biasqkv): fused QKV MFMA GEMM (pure bf16 A) + bias precompute.
//   blocks [0, 768)       : GEMM — z=bid>>8 in {Q,K,V}
//   blocks [768, 768+2048): bias in MFMA-fragment layout (round-3 verified)
// __launch_bounds__(256, 6): cap VGPR ~85 so neither path spills, 6 blocks/CU.
// ---------------------------------------------------------------------------
__global__ __launch_bounds__(256, 6) void biasqkv_k(
    const ushort_t* __restrict__ A0, const ushort_t* __restrict__ A1, const ushort_t* __restrict__ A2,
    const ushort_t* __restrict__ B0, const ushort_t* __restrict__ B1, const ushort_t* __restrict__ B2,
    const float* __restrict__ bi0, const float* __restrict__ bi1, const float* __restrict__ bi2,
    ushort_t* __restrict__ Yh0, ushort_t* __restrict__ Yh1, ushort_t* __restrict__ Yh2,
    const ushort_t* __restrict__ xproj, const ushort_t* __restrict__ yproj,
    const float* __restrict__ qx, const float* __restrict__ qy,
    const float* __restrict__ kx, const float* __restrict__ ky,
    const float* __restrict__ bbp,
    ushort_t* __restrict__ biasf)
{
    __shared__ ushort_t As[64][72];
    __shared__ ushort_t Bs[64][72];
    const int bid = blockIdx.x;
    const int tid = threadIdx.x;

    if (bid < 768) {
        // ---------------- GEMM path (bf16 A) ----------------
        const int z = bid >> 8, by = (bid >> 4) & 15, bx = bid & 15;
        const ushort_t* Ah = (z == 0) ? A0 : ((z == 1) ? A1 : A2);
        const ushort_t* Bp = (z == 0) ? B0 : ((z == 1) ? B1 : B2);
        const float* bi = (z == 0) ? bi0 : ((z == 1) ? bi1 : bi2);
        ushort_t* Yh = (z == 0) ? Yh0 : ((z == 1) ? Yh1 : Yh2);
        const int m0 = by * 64, n0 = bx * 64;
        const int lane = tid & 63, w = tid >> 6;
        const int wm = w >> 1, wn = w & 1;
        const int srow = tid >> 2, scg = (tid & 3) * 16;

        f32x4 acc[2][2] = {};
        uint4 arh0, arh1, brh0, brh1;

        auto loadA = [&](int kk) {
            const ushort_t* ap = Ah + (m0 + srow) * 1024 + kk + scg;
            arh0 = *(const uint4*)(ap);
            arh1 = *(const uint4*)(ap + 8);
        };
        auto loadB = [&](int kk) {
            const ushort_t* bp = Bp + (n0 + srow) * 1024 + kk + scg;
            brh0 = *(const uint4*)(bp);
            brh1 = *(const uint4*)(bp + 8);
        };
        loadA(0); loadB(0);

        const int fr = lane & 15;            // frag row/col within 16
        const int ko = (lane >> 4) * 8;      // k offset within 32

        for (int k0 = 0; k0 < 1024; k0 += 64) {
            __syncthreads();
            *(uint4*)&As[srow][scg]     = arh0;
            *(uint4*)&As[srow][scg + 8] = arh1;
            *(uint4*)&Bs[srow][scg]     = brh0;
            *(uint4*)&Bs[srow][scg + 8] = brh1;
            __syncthreads();
            if (k0 + 64 < 1024) { loadA(k0 + 64); loadB(k0 + 64); }
#pragma unroll
            for (int ks = 0; ks < 64; ks += 32) {
                short8v af0 = *(const short8v*)&As[wm * 32 + fr][ks + ko];
                short8v af1 = *(const short8v*)&As[wm * 32 + 16 + fr][ks + ko];
                short8v bf0 = *(const short8v*)&Bs[wn * 32 + fr][ks + ko];
                short8v bf1 = *(const short8v*)&Bs[wn * 32 + 16 + fr][ks + ko];
                acc[0][0] = __builtin_amdgcn_mfma_f32_16x16x32_bf16(af0, bf0, acc[0][0], 0, 0, 0);
                acc[0][1] = __builtin_amdgcn_mfma_f32_16x16x32_bf16(af0, bf1, acc[0][1], 0, 0, 0);
                acc[1][0] = __builtin_amdgcn_mfma_f32_16x16x32_bf16(af1, bf0, acc[1][0], 0, 0, 0);
                acc[1][1] = __builtin_amdgcn_mfma_f32_16x16x32_bf16(af1, bf1, acc[1][1], 0, 0, 0);
            }
        }

        const int cr = (lane >> 4) * 4;
        const int cc = lane & 15;
#pragma unroll
        for (int m = 0; m < 2; ++m) {
#pragma unroll
            for (int n = 0; n < 2; ++n) {
                int grow = m0 + wm * 32 + m * 16 + cr;
                int gcol = n0 + wn * 32 + n * 16 + cc;
                float bv = bi[gcol];
                int hh = gcol >> 6, dd = gcol & 63;
                if (z == 0) {
#pragma unroll
                    for (int j = 0; j < 4; ++j) {
                        int r = grow + j, bb_ = r >> 9, nn = r & 511;
                        Yh[((bb_ * HH + hh) * NQS + nn) * DK + dd] = f2bf(acc[m][n][j] + bv);
                    }
                } else if (z == 1) {
                    // K pre-scaled by 1/sqrt(DK) = 0.125 (exact power-of-two)
#pragma unroll
                    for (int j = 0; j < 4; ++j) {
                        int r = grow + j, bb_ = r >> 9, nn = r & 511;
                        Yh[((bb_ * HH + hh) * NQS + nn) * DK + dd] = f2bf((acc[m][n][j] + bv) * 0.125f);
                    }
                } else {
                    // V: (B,H,64,N) bf16 transposed
#pragma unroll
                    for (int j = 0; j < 4; ++j) {
                        int r = grow + j, bb_ = r >> 9, nn = r & 511;
                        Yh[((bb_ * HH + hh) * DK + dd) * NKS + nn] = f2bf(acc[m][n][j] + bv);
                    }
                }
            }
        }
    } else {
        // ---------------- bias path ----------------
        const int r = bid - 768;               // 0..2047
        const int b = r >> 10;
        const int kt = (r >> 5) & 31, qt = r & 31;
        const int ql = tid & 15, kl = tid >> 4;
        const int qg = qt * 16 + ql, kg = kt * 16 + kl;

        float dx = qx[b * NKS + kg] - kx[b * NQS + qg];
        float dy = qy[b * NKS + kg] - ky[b * NQS + qg];
        int ix = (int)rintf((fminf(fmaxf(dx, -1000.f), 1000.f) + 1000.f) * 20.f);
        int iy = (int)rintf((fminf(fmaxf(dy, -1000.f), 1000.f) + 1000.f) * 20.f);
        const float bb = bbp[0];

        uint4 xw0 = *(const uint4*)(xproj + ix * 16);
        uint4 xw1 = *(const uint4*)(xproj + ix * 16 + 8);
        uint4 yw0 = *(const uint4*)(yproj + iy * 16);
        uint4 yw1 = *(const uint4*)(yproj + iy * 16 + 8);

        float xa[16], ya[16];
        {
            unsigned u[8] = {xw0.x, xw0.y, xw0.z, xw0.w, xw1.x, xw1.y, xw1.z, xw1.w};
            unsigned v[8] = {yw0.x, yw0.y, yw0.z, yw0.w, yw1.x, yw1.y, yw1.z, yw1.w};
#pragma unroll
            for (int wv = 0; wv < 8; ++wv) {
                xa[2 * wv]     = asf(u[wv] << 16);
                xa[2 * wv + 1] = asf(u[wv] & 0xFFFF0000u);
                ya[2 * wv]     = asf(v[wv] << 16);
                ya[2 * wv + 1] = asf(v[wv] & 0xFFFF0000u);
            }
        }
        const int lane_j = ((kl >> 2) * 16 + ql) * 4 + (kl & 3);
#pragma unroll
        for (int h = 0; h < HH; ++h) {
            float t2 = xa[h] + ya[h] + bb;
            float sig = 1.f / (1.f + __expf(-t2));
            biasf[((b * HH + h) * 32 + kt) * (32 * 256) + qt * 256 + lane_j] = f2bf(sig);
        }
    }
}

// ---------------------------------------------------------------------------
// Kernel C: MFMA flash attention, swapped operands (round-3 verified).
// Score scale already folded into K. Bias read in fragment layout.
// ---------------------------------------------------------------------------
__global__ __launch_bounds__(256, 4) void attn_k(
    const ushort_t* __restrict__ qbh, const ushort_t* __restrict__ kbh,
    const ushort_t* __restrict__ vtb, const ushort_t* __restrict__ biasf,
    ushort_t* __restrict__ attb)
{
    __shared__ ushort_t pst[4][16][40];     // per-wave P tiles [q][k32] (+pad)
    __shared__ float obuf[4][16][76];       // per-wave O^T partials [q][d]
    __shared__ float mt[4][16], lt[4][16];

    const int tid = threadIdx.x;
    const int wid = tid >> 6, lane = tid & 63;
    const int q = lane & 15, g = lane >> 4;
    const int qt = blockIdx.x;
    const int h = blockIdx.y, b = blockIdx.z;
    const int bh = b * HH + h;

    const ushort_t* Qp = qbh + (bh * NQS + qt * 16 + q) * DK + g * 8;
    short8v qf0 = *(const short8v*)Qp;
    short8v qf1 = *(const short8v*)(Qp + 32);

    f32x4 oacc[4] = {};
    float m = -1e30f, l = 0.f;

#pragma unroll 2
    for (int c = 0; c < 4; ++c) {
        const int kc = wid * 128 + c * 32;
        const ushort_t* Kp = kbh + (bh * NKS + kc + q) * DK + g * 8;
        short8v kf00 = *(const short8v*)(Kp);
        short8v kf01 = *(const short8v*)(Kp + 32);
        short8v kf10 = *(const short8v*)(Kp + 16 * DK);
        short8v kf11 = *(const short8v*)(Kp + 16 * DK + 32);

        f32x4 s0 = {0.f, 0.f, 0.f, 0.f};
        f32x4 s1 = {0.f, 0.f, 0.f, 0.f};
        s0 = __builtin_amdgcn_mfma_f32_16x16x32_bf16(kf00, qf0, s0, 0, 0, 0);
        s0 = __builtin_amdgcn_mfma_f32_16x16x32_bf16(kf01, qf1, s0, 0, 0, 0);
        s1 = __builtin_amdgcn_mfma_f32_16x16x32_bf16(kf10, qf0, s1, 0, 0, 0);
        s1 = __builtin_amdgcn_mfma_f32_16x16x32_bf16(kf11, qf1, s1, 0, 0, 0);

        // bias (fragment layout): tiles kt, kt+1
        const int kt = kc >> 4;
        uint2 b0 = *((const uint2*)(biasf + ((bh * 32 + kt) * 32 + qt) * 256) + lane);
        uint2 b1 = *((const uint2*)(biasf + ((bh * 32 + kt + 1) * 32 + qt) * 256) + lane);

        float sv[8];
        sv[0] = s0[0] + asf(b0.x << 16);
        sv[1] = s0[1] + asf(b0.x & 0xFFFF0000u);
        sv[2] = s0[2] + asf(b0.y << 16);
        sv[3] = s0[3] + asf(b0.y & 0xFFFF0000u);
        sv[4] = s1[0] + asf(b1.x << 16);
        sv[5] = s1[1] + asf(b1.x & 0xFFFF0000u);
        sv[6] = s1[2] + asf(b1.y << 16);
        sv[7] = s1[3] + asf(b1.y & 0xFFFF0000u);

        // row max across this lane's 8 + the 3 other g-lanes of column q
        float mc = fmaxf(fmaxf(fmaxf(sv[0], sv[1]), fmaxf(sv[2], sv[3])),
                         fmaxf(fmaxf(sv[4], sv[5]), fmaxf(sv[6], sv[7])));
        mc = fmaxf(mc, __shfl_xor(mc, 16));
        mc = fmaxf(mc, __shfl_xor(mc, 32));
        float mn = fmaxf(m, mc);

        float p[8], ps = 0.f;
#pragma unroll
        for (int j = 0; j < 8; ++j) { p[j] = __expf(sv[j] - mn); ps += p[j]; }
        float sc = __expf(m - mn);
        l = l * sc + ps;
        m = mn;
#pragma unroll
        for (int dt = 0; dt < 4; ++dt)
#pragma unroll
            for (int j = 0; j < 4; ++j) oacc[dt][j] *= sc;

        // P^T fragment via per-wave LDS tile
        ushort_t* prow = &pst[wid][q][0];
        *(unsigned*)(prow + 4 * g)          = pack2(p[0], p[1]);
        *(unsigned*)(prow + 4 * g + 2)      = pack2(p[2], p[3]);
        *(unsigned*)(prow + 16 + 4 * g)     = pack2(p[4], p[5]);
        *(unsigned*)(prow + 16 + 4 * g + 2) = pack2(p[6], p[7]);
        short8v pf = *(const short8v*)&pst[wid][q][8 * g];

        // O^T += V^T . P^T over this chunk's 32 k
        const ushort_t* Vp = vtb + (bh * DK + q) * NKS + kc + g * 8;
#pragma unroll
        for (int dt = 0; dt < 4; ++dt) {
            short8v vf = *(const short8v*)(Vp + dt * 16 * NKS);
            oacc[dt] = __builtin_amdgcn_mfma_f32_16x16x32_bf16(vf, pf, oacc[dt], 0, 0, 0);
        }
    }

    // intra-wave l across the 4 g-lanes of each q (m already shared)
    float lr = l + __shfl_xor(l, 16);
    lr = lr + __shfl_xor(lr, 32);
    if (lane < 16) { mt[wid][lane] = m; lt[wid][lane] = lr; }
#pragma unroll
    for (int dt = 0; dt < 4; ++dt)
#pragma unroll
        for (int j = 0; j < 4; ++j)
            obuf[wid][q][dt * 16 + 4 * g + j] = oacc[dt][j];
    __syncthreads();

    // merge 4 wave-partials: thread -> (q = tid>>4, d4 = (tid&15)*4)
    const int mq = tid >> 4, d4 = (tid & 15) * 4;
    float m0 = mt[0][mq], m1 = mt[1][mq], m2 = mt[2][mq], m3 = mt[3][mq];
    float ms = fmaxf(fmaxf(m0, m1), fmaxf(m2, m3));
    float e0 = __expf(m0 - ms), e1 = __expf(m1 - ms);
    float e2 = __expf(m2 - ms), e3 = __expf(m3 - ms);
    float denom = lt[0][mq] * e0 + lt[1][mq] * e1 + lt[2][mq] * e2 + lt[3][mq] * e3;
    float inv = 1.f / denom;
    float4 o0 = *(float4*)&obuf[0][mq][d4];
    float4 o1 = *(float4*)&obuf[1][mq][d4];
    float4 o2 = *(float4*)&obuf[2][mq][d4];
    float4 o3 = *(float4*)&obuf[3][mq][d4];
    float r0 = (o0.x * e0 + o1.x * e1 + o2.x * e2 + o3.x * e3) * inv;
    float r1 = (o0.y * e0 + o1.y * e1 + o2.y * e2 + o3.y * e3) * inv;
    float r2 = (o0.z * e0 + o1.z * e1 + o2.z * e2 + o3.z * e3) * inv;
    float r3 = (o0.w * e0 + o1.w * e1 + o2.w * e2 + o3.w * e3) * inv;
    uint2 ow;
    ow.x = pack2(r0, r1); ow.y = pack2(r2, r3);
    *reinterpret_cast<uint2*>(attb + (b * NQS + qt * 16 + mq) * DM + h * DK + d4) = ow;
}

// ---------------------------------------------------------------------------
// Kernel D: output projection GEMM (A bf16 attb, B pre-transposed Wo bf16,
// plain fp32 [M][N] output). 64x64 tile, BK=64, 4 waves of 32x32.
// ---------------------------------------------------------------------------
__global__ __launch_bounds__(256) void ogemm_k(
    const ushort_t* __restrict__ Ah, const ushort_t* __restrict__ Bp,
    const float* __restrict__ bi, float* __restrict__ Yf)
{
    __shared__ ushort_t As[64][72];
    __shared__ ushort_t Bs[64][72];
    const int m0 = blockIdx.y * 64, n0 = blockIdx.x * 64;
    const int tid = threadIdx.x;
    const int lane = tid & 63, w = tid >> 6;
    const int wm = w >> 1, wn = w & 1;
    const int srow = tid >> 2, scg = (tid & 3) * 16;

    f32x4 acc[2][2] = {};
    uint4 arh0, arh1, brh0, brh1;

    auto loadA = [&](int kk) {
        const ushort_t* ap = Ah + (m0 + srow) * 1024 + kk + scg;
        arh0 = *(const uint4*)(ap);
        arh1 = *(const uint4*)(ap + 8);
    };
    auto loadB = [&](int kk) {
        const ushort_t* bp = Bp + (n0 + srow) * 1024 + kk + scg;
        brh0 = *(const uint4*)(bp);
        brh1 = *(const uint4*)(bp + 8);
    };
    loadA(0); loadB(0);

    const int fr = lane & 15;
    const int ko = (lane >> 4) * 8;

    for (int k0 = 0; k0 < 1024; k0 += 64) {
        __syncthreads();
        *(uint4*)&As[srow][scg]     = arh0;
        *(uint4*)&As[srow][scg + 8] = arh1;
        *(uint4*)&Bs[srow][scg]     = brh0;
        *(uint4*)&Bs[srow][scg + 8] = brh1;
        __syncthreads();
        if (k0 + 64 < 1024) { loadA(k0 + 64); loadB(k0 + 64); }
#pragma unroll
        for (int ks = 0; ks < 64; ks += 32) {
            short8v af0 = *(const short8v*)&As[wm * 32 + fr][ks + ko];
            short8v af1 = *(const short8v*)&As[wm * 32 + 16 + fr][ks + ko];
            short8v bf0 = *(const short8v*)&Bs[wn * 32 + fr][ks + ko];
            short8v bf1 = *(const short8v*)&Bs[wn * 32 + 16 + fr][ks + ko];
            acc[0][0] = __builtin_amdgcn_mfma_f32_16x16x32_bf16(af0, bf0, acc[0][0], 0, 0, 0);
            acc[0][1] = __builtin_amdgcn_mfma_f32_16x16x32_bf16(af0, bf1, acc[0][1], 0, 0, 0);
            acc[1][0] = __builtin_amdgcn_mfma_f32_16x16x32_bf16(af1, bf0, acc[1][0], 0, 0, 0);
            acc[1][1] = __builtin_amdgcn_mfma_f32_16x16x32_bf16(af1, bf1, acc[1][1], 0, 0, 0);
        }
    }

    const int cr = (lane >> 4) * 4;
    const int cc = lane & 15;
#pragma unroll
    for (int m = 0; m < 2; ++m) {
#pragma unroll
        for (int n = 0; n < 2; ++n) {
            int grow = m0 + wm * 32 + m * 16 + cr;
            int gcol = n0 + wn * 32 + n * 16 + cc;
            float bv = bi[gcol];
#pragma unroll
            for (int j = 0; j < 4; ++j)
                Yf[(grow + j) * 1024 + gcol] = acc[m][n][j] + bv;
        }
    }
}

// ---------------------------------------------------------------------------
extern "C" void kernel_launch(void* const* d_in, const int* in_sizes, int n_in,
                              void* d_out, int out_size, void* d_ws, size_t ws_size,
                              hipStream_t stream)
{
    const float* query = (const float*)d_in[0];
    const float* key   = (const float*)d_in[1];
    const float* value = (const float*)d_in[2];
    const float* qx    = (const float*)d_in[3];
    const float* qy    = (const float*)d_in[4];
    const float* kx    = (const float*)d_in[5];
    const float* ky    = (const float*)d_in[6];
    const float* Wq    = (const float*)d_in[7];
    const float* bq    = (const float*)d_in[8];
    const float* Wk    = (const float*)d_in[9];
    const float* bk    = (const float*)d_in[10];
    const float* Wv    = (const float*)d_in[11];
    const float* bv    = (const float*)d_in[12];
    const float* Wo    = (const float*)d_in[13];
    const float* bo    = (const float*)d_in[14];
    const float* xt    = (const float*)d_in[15];
    const float* yt    = (const float*)d_in[16];
    const float* Wb    = (const float*)d_in[17];
    const float* bbp   = (const float*)d_in[18];
    float* out = (float*)d_out;

    // ws layout — ALL offsets in ushort (bf16) units.
    ushort_t* xprojh = (ushort_t*)d_ws;                  //   640,064
    ushort_t* yprojh = xprojh + 640064;                  //   640,064
    ushort_t* biasf  = yprojh + 640064;                  // 8,388,608  (B,H,32,32,256)
    ushort_t* qbh    = biasf + 8388608;                  // 1,048,576  (B,H,512,64)
    ushort_t* kbh    = qbh + 1048576;                    // 1,048,576
    ushort_t* vtb    = kbh + 1048576;                    // 1,048,576  (B,H,64,512)
    ushort_t* attb   = vtb + 1048576;                    // 1,048,576  (B,512,1024)
    ushort_t* wqt    = attb + 1048576;                   // 1,048,576 each
    ushort_t* wkt    = wqt + 1048576;
    ushort_t* wvt    = wkt + 1048576;
    ushort_t* wot    = wvt + 1048576;
    ushort_t* qc     = wot + 1048576;                    // 1,048,576 each (bf16 QKV inputs)
    ushort_t* kc     = qc + 1048576;
    ushort_t* vc     = kc + 1048576;

    prep_k<<<dim3(5001 + 2048 + 1536), dim3(256), 0, stream>>>(
        xt, yt, Wb, Wq, Wk, Wv, Wo, query, key, value,
        xprojh, yprojh, wqt, wkt, wvt, wot, qc, kc, vc);
    biasqkv_k<<<dim3(768 + 2048), dim3(256), 0, stream>>>(
        qc, kc, vc, wqt, wkt, wvt, bq, bk, bv, qbh, kbh, vtb,
        xprojh, yprojh, qx, qy, kx, ky, bbp, biasf);
    attn_k<<<dim3(32, 16, 2), dim3(256), 0, stream>>>(
        qbh, kbh, vtb, biasf, attb);
    ogemm_k<<<dim3(16, 16), dim3(256), 0, stream>>>(
        attb, wot, bo, out);
}